// Round 2
// baseline (1524.142 us; speedup 1.0000x reference)
//
#include <hip/hip_runtime.h>
#include <stdint.h>

#define N_NODES 50000
#define N_EDGES 800000

// flag indices: 0:x 1:ea 2:Wl1 3:bl1 4:Wr1 5:br1 6:We1 7:att1 8:bias1
//               9:Wl2 10:bl2 11:Wr2 12:br2 13:We2 14:att2 15:bias2
struct Ptrs { const void* p[16]; int n[16]; };

__device__ __forceinline__ float bf2f(unsigned short u){
  union { unsigned int i; float f; } v; v.i = ((unsigned int)u) << 16; return v.f;
}
__device__ __forceinline__ float lo16(unsigned int u){ union { unsigned int i; float f; } v; v.i = u << 16; return v.f; }
__device__ __forceinline__ float hi16(unsigned int u){ union { unsigned int i; float f; } v; v.i = u & 0xffff0000u; return v.f; }
__device__ __forceinline__ unsigned short f2bf(float f){
  if (!(f == f)) return 0;
  unsigned int x = __float_as_uint(f);
  unsigned int r = (x + 0x7fffu + ((x >> 16) & 1u)) >> 16;
  return (unsigned short)r;
}
__device__ __forceinline__ float fin(float v){
  if (!(v == v)) return 0.f;
  return fminf(fmaxf(v, -1e30f), 1e30f);
}
__device__ __forceinline__ float loadF(const void* p, int f32, size_t idx){
  return f32 ? ((const float*)p)[idx] : bf2f(((const unsigned short*)p)[idx]);
}

// ---------- dtype detect: count invalid-bf16 patterns in first n ushorts ----------
__global__ __launch_bounds__(256) void k_detect(Ptrs tl, int* __restrict__ flags)
{
  __shared__ int red[256];
  int b = blockIdx.x, t = threadIdx.x;
  const unsigned short* p = (const unsigned short*)tl.p[b];
  int n = tl.n[b]; if (n > 16384) n = 16384;
  int crazy = 0;
  for (int i = t; i < n; i += 256) {
    unsigned short u = p[i];
    if (u) {
      int ex = (u >> 7) & 0xFF;
      if (ex == 0xFF || ex < 0x60) crazy++;
    }
  }
  red[t] = crazy; __syncthreads();
  for (int off = 128; off; off >>= 1) { if (t < off) red[t] += red[t + off]; __syncthreads(); }
  if (t == 0) flags[b] = (red[0] * 10 > n) ? 1 : 0;   // >10% crazy => float32
}

__global__ __launch_bounds__(256) void k_zero(int* __restrict__ p, int n)
{
  int i = blockIdx.x * 256 + threadIdx.x;
  if (i < n) p[i] = 0;
}

// ---------- layer-1 GEMM: xl/xr = x@W + b  [N,128]x[128,128] ----------
__global__ __launch_bounds__(256) void k_gemm1(
    const void* __restrict__ x,
    const void* __restrict__ Wl, const void* __restrict__ bl,
    const void* __restrict__ Wr, const void* __restrict__ br,
    const int* __restrict__ flags,
    float* __restrict__ xl, float* __restrict__ xr)
{
  __shared__ float xs[32 * 132];
  __shared__ unsigned short ws[128 * 128];
  const void* W  = blockIdx.y ? Wr : Wl;
  const void* bb = blockIdx.y ? br : bl;
  int fW = blockIdx.y ? flags[4] : flags[2];
  int fB = blockIdx.y ? flags[5] : flags[3];
  int fX = flags[0];
  float* out = blockIdx.y ? xr : xl;
  int tid = threadIdx.x;
  int row0 = blockIdx.x * 32;
  if (fW) {
    for (int i = tid * 8; i < 128 * 128; i += 2048) {
      float4 a = *(const float4*)((const float*)W + i);
      float4 b = *(const float4*)((const float*)W + i + 4);
      uint4 u;
      u.x = (unsigned)f2bf(a.x) | ((unsigned)f2bf(a.y) << 16);
      u.y = (unsigned)f2bf(a.z) | ((unsigned)f2bf(a.w) << 16);
      u.z = (unsigned)f2bf(b.x) | ((unsigned)f2bf(b.y) << 16);
      u.w = (unsigned)f2bf(b.z) | ((unsigned)f2bf(b.w) << 16);
      *(uint4*)(ws + i) = u;
    }
  } else {
    for (int i = tid * 8; i < 128 * 128; i += 2048)
      *(uint4*)(ws + i) = *(const uint4*)((const unsigned short*)W + i);
  }
  for (int i = tid * 4; i < 32 * 128; i += 1024) {
    int r = i >> 7, k = i & 127;
    int row = row0 + r;
    float4 v = make_float4(0.f, 0.f, 0.f, 0.f);
    if (row < N_NODES) {
      if (fX) v = *(const float4*)((const float*)x + (size_t)row * 128 + k);
      else {
        uint2 u = *(const uint2*)((const unsigned short*)x + (size_t)row * 128 + k);
        v.x = lo16(u.x); v.y = hi16(u.x); v.z = lo16(u.y); v.w = hi16(u.y);
      }
    }
    *(float4*)(xs + r * 132 + k) = v;
  }
  __syncthreads();
  int r = tid >> 3, cg = tid & 7;
  float acc[16];
#pragma unroll
  for (int j = 0; j < 16; j++) acc[j] = 0.f;
#pragma unroll 4
  for (int k = 0; k < 128; k++) {
    float xv = xs[r * 132 + k];
    uint4 p0 = *(const uint4*)(ws + k * 128 + cg * 8);
    uint4 p1 = *(const uint4*)(ws + k * 128 + 64 + cg * 8);
    acc[0]  = fmaf(xv, lo16(p0.x), acc[0]);  acc[1]  = fmaf(xv, hi16(p0.x), acc[1]);
    acc[2]  = fmaf(xv, lo16(p0.y), acc[2]);  acc[3]  = fmaf(xv, hi16(p0.y), acc[3]);
    acc[4]  = fmaf(xv, lo16(p0.z), acc[4]);  acc[5]  = fmaf(xv, hi16(p0.z), acc[5]);
    acc[6]  = fmaf(xv, lo16(p0.w), acc[6]);  acc[7]  = fmaf(xv, hi16(p0.w), acc[7]);
    acc[8]  = fmaf(xv, lo16(p1.x), acc[8]);  acc[9]  = fmaf(xv, hi16(p1.x), acc[9]);
    acc[10] = fmaf(xv, lo16(p1.y), acc[10]); acc[11] = fmaf(xv, hi16(p1.y), acc[11]);
    acc[12] = fmaf(xv, lo16(p1.z), acc[12]); acc[13] = fmaf(xv, hi16(p1.z), acc[13]);
    acc[14] = fmaf(xv, lo16(p1.w), acc[14]); acc[15] = fmaf(xv, hi16(p1.w), acc[15]);
  }
  int row = row0 + r;
  if (row < N_NODES) {
    float* op = out + (size_t)row * 128;
#pragma unroll
    for (int j = 0; j < 8; j++) op[cg * 8 + j]      = fin(acc[j]     + loadF(bb, fB, cg * 8 + j));
#pragma unroll
    for (int j = 0; j < 8; j++) op[64 + cg * 8 + j] = fin(acc[8 + j] + loadF(bb, fB, 64 + cg * 8 + j));
  }
}

// ---------- layer-2 GEMM: xl2/xr2 = h@W + b  [N,128]x[128,64] ----------
__global__ __launch_bounds__(256) void k_gemm2(
    const float* __restrict__ h,
    const void* __restrict__ Wl, const void* __restrict__ bl,
    const void* __restrict__ Wr, const void* __restrict__ br,
    const int* __restrict__ flags,
    float* __restrict__ xl, float* __restrict__ xr)
{
  __shared__ float hs[32 * 132];
  __shared__ unsigned short ws[128 * 64];
  const void* W  = blockIdx.y ? Wr : Wl;
  const void* bb = blockIdx.y ? br : bl;
  int fW = blockIdx.y ? flags[11] : flags[9];
  int fB = blockIdx.y ? flags[12] : flags[10];
  float* out = blockIdx.y ? xr : xl;
  int tid = threadIdx.x;
  int row0 = blockIdx.x * 32;
  if (fW) {
    for (int i = tid * 8; i < 128 * 64; i += 2048) {
      float4 a = *(const float4*)((const float*)W + i);
      float4 b = *(const float4*)((const float*)W + i + 4);
      uint4 u;
      u.x = (unsigned)f2bf(a.x) | ((unsigned)f2bf(a.y) << 16);
      u.y = (unsigned)f2bf(a.z) | ((unsigned)f2bf(a.w) << 16);
      u.z = (unsigned)f2bf(b.x) | ((unsigned)f2bf(b.y) << 16);
      u.w = (unsigned)f2bf(b.z) | ((unsigned)f2bf(b.w) << 16);
      *(uint4*)(ws + i) = u;
    }
  } else {
    for (int i = tid * 8; i < 128 * 64; i += 2048)
      *(uint4*)(ws + i) = *(const uint4*)((const unsigned short*)W + i);
  }
  for (int i = tid * 4; i < 32 * 128; i += 1024) {
    int r = i >> 7, k = i & 127;
    int row = row0 + r;
    float4 v = make_float4(0.f, 0.f, 0.f, 0.f);
    if (row < N_NODES) v = *(const float4*)(h + (size_t)row * 128 + k);
    *(float4*)(hs + r * 132 + k) = v;
  }
  __syncthreads();
  int r = tid >> 3, cg = tid & 7;
  float acc[8];
#pragma unroll
  for (int j = 0; j < 8; j++) acc[j] = 0.f;
#pragma unroll 4
  for (int k = 0; k < 128; k++) {
    float hv = hs[r * 132 + k];
    uint4 p = *(const uint4*)(ws + k * 64 + cg * 8);
    acc[0] = fmaf(hv, lo16(p.x), acc[0]); acc[1] = fmaf(hv, hi16(p.x), acc[1]);
    acc[2] = fmaf(hv, lo16(p.y), acc[2]); acc[3] = fmaf(hv, hi16(p.y), acc[3]);
    acc[4] = fmaf(hv, lo16(p.z), acc[4]); acc[5] = fmaf(hv, hi16(p.z), acc[5]);
    acc[6] = fmaf(hv, lo16(p.w), acc[6]); acc[7] = fmaf(hv, hi16(p.w), acc[7]);
  }
  int row = row0 + r;
  if (row < N_NODES) {
    float* op = out + (size_t)row * 64;
#pragma unroll
    for (int j = 0; j < 8; j++) op[cg * 8 + j] = fin(acc[j] + loadF(bb, fB, cg * 8 + j));
  }
}

// ---------- CSR build ----------
__global__ __launch_bounds__(256) void k_hist(const int* __restrict__ ei, int* __restrict__ counts)
{
  int e = blockIdx.x * 256 + threadIdx.x;
  if (e < N_EDGES) {
    int d = ei[N_EDGES + e]; if ((unsigned)d >= N_NODES) d = 0;
    atomicAdd(&counts[d], 1);
  }
}

__global__ __launch_bounds__(256) void k_scan1(const int* __restrict__ counts,
                                               int* __restrict__ row_ptr, int* __restrict__ bsum)
{
  __shared__ int lds[256];
  int t = threadIdx.x;
  int base = blockIdx.x * 1024 + t * 4;
  int c0 = (base + 0) < N_NODES ? counts[base + 0] : 0;
  int c1 = (base + 1) < N_NODES ? counts[base + 1] : 0;
  int c2 = (base + 2) < N_NODES ? counts[base + 2] : 0;
  int c3 = (base + 3) < N_NODES ? counts[base + 3] : 0;
  int s = c0 + c1 + c2 + c3;
  lds[t] = s; __syncthreads();
  for (int off = 1; off < 256; off <<= 1) {
    int v = (t >= off) ? lds[t - off] : 0;
    __syncthreads();
    lds[t] += v;
    __syncthreads();
  }
  int incl = lds[t];
  int excl = incl - s;
  if (base + 0 < N_NODES) row_ptr[base + 0] = excl;
  if (base + 1 < N_NODES) row_ptr[base + 1] = excl + c0;
  if (base + 2 < N_NODES) row_ptr[base + 2] = excl + c0 + c1;
  if (base + 3 < N_NODES) row_ptr[base + 3] = excl + c0 + c1 + c2;
  if (t == 255) bsum[blockIdx.x] = incl;
}

__global__ __launch_bounds__(64) void k_scan2(int* __restrict__ bsum, int nb)
{
  __shared__ int l[64];
  int t = threadIdx.x;
  if (t < nb) l[t] = bsum[t];
  __syncthreads();
  if (t == 0) { int run = 0; for (int i = 0; i < nb; i++) { int v = l[i]; l[i] = run; run += v; } }
  __syncthreads();
  if (t < nb) bsum[t] = l[t];
}

__global__ __launch_bounds__(256) void k_scan3(int* __restrict__ row_ptr, int* __restrict__ cursor,
                                               const int* __restrict__ bsum)
{
  int t = threadIdx.x;
  int base = blockIdx.x * 1024 + t * 4;
  int add = bsum[blockIdx.x];
#pragma unroll
  for (int j = 0; j < 4; j++) {
    int i = base + j;
    if (i < N_NODES) { int v = row_ptr[i] + add; row_ptr[i] = v; cursor[i] = v; }
  }
  if (blockIdx.x == 0 && t == 0) row_ptr[N_NODES] = N_EDGES;
}

__global__ __launch_bounds__(256) void k_scatter(const int* __restrict__ ei,
                                                 int* __restrict__ cursor, int* __restrict__ col)
{
  int e = blockIdx.x * 256 + threadIdx.x;
  if (e < N_EDGES) {
    int d = ei[N_EDGES + e]; if ((unsigned)d >= N_NODES) d = 0;
    int p = atomicAdd(&cursor[d], 1);
    if ((unsigned)p < N_EDGES) col[p] = e;
  }
}

// ---------- layer-1 edge pass ----------
__global__ __launch_bounds__(256) void k_edge1(
    const void* __restrict__ ea, const int* __restrict__ ei,
    const float* __restrict__ xl, const float* __restrict__ xr,
    const void* __restrict__ We, const void* __restrict__ att,
    const int* __restrict__ flags,
    float* __restrict__ w1, float* __restrict__ den1)
{
  __shared__ unsigned short we[32 * 128];
  __shared__ float at[128];
  int fEA = flags[1], fWe = flags[6], fAtt = flags[7];
  int tid = threadIdx.x;
  if (fWe) {
    for (int i = tid * 8; i < 32 * 128; i += 2048) {
      float4 a = *(const float4*)((const float*)We + i);
      float4 b = *(const float4*)((const float*)We + i + 4);
      uint4 u;
      u.x = (unsigned)f2bf(a.x) | ((unsigned)f2bf(a.y) << 16);
      u.y = (unsigned)f2bf(a.z) | ((unsigned)f2bf(a.w) << 16);
      u.z = (unsigned)f2bf(b.x) | ((unsigned)f2bf(b.y) << 16);
      u.w = (unsigned)f2bf(b.z) | ((unsigned)f2bf(b.w) << 16);
      *(uint4*)(we + i) = u;
    }
  } else {
    for (int i = tid * 8; i < 32 * 128; i += 2048)
      *(uint4*)(we + i) = *(const uint4*)((const unsigned short*)We + i);
  }
  if (tid < 128) at[tid] = loadF(att, fAtt, tid);
  __syncthreads();
  int e = blockIdx.x * 4 + (tid >> 6);
  if (e >= N_EDGES) return;
  int lane = tid & 63;
  int s = ei[e], d = ei[N_EDGES + e];
  if ((unsigned)s >= N_NODES) s = 0;
  if ((unsigned)d >= N_NODES) d = 0;
  float eav = (lane < 32) ? loadF(ea, fEA, (size_t)e * 32 + lane) : 0.f;
  eav = fin(eav);
  float2 xlv = *(const float2*)(xl + (size_t)s * 128 + 2 * lane);
  float2 xrv = *(const float2*)(xr + (size_t)d * 128 + 2 * lane);
  float a0 = 0.f, a1 = 0.f;
  const unsigned int* wep = (const unsigned int*)we;
#pragma unroll
  for (int k = 0; k < 32; k++) {
    float av = __shfl(eav, k, 64);
    unsigned int p = wep[k * 64 + lane];
    a0 = fmaf(av, lo16(p), a0);
    a1 = fmaf(av, hi16(p), a1);
  }
  float s0 = xlv.x + xrv.x + a0;
  float s1 = xlv.y + xrv.y + a1;
  float m0 = s0 > 0.f ? s0 : 0.2f * s0;
  float m1 = s1 > 0.f ? s1 : 0.2f * s1;
  int hh = lane >> 4;
  int c0 = (2 * lane) & 31;
  float p = at[hh * 32 + c0] * m0 + at[hh * 32 + c0 + 1] * m1;
  p += __shfl_xor(p, 1, 64);
  p += __shfl_xor(p, 2, 64);
  p += __shfl_xor(p, 4, 64);
  p += __shfl_xor(p, 8, 64);
  p = fin(p);
  float w = __expf(fminf(p, 25.f));
  if ((lane & 15) == 0) {
    w1[(size_t)e * 4 + hh] = w;
    atomicAdd(&den1[(size_t)d * 4 + hh], w);
  }
}

// ---------- layer-1 aggregate + bias + ELU -> h[N,128] ----------
__global__ __launch_bounds__(256) void k_agg1(
    const int* __restrict__ ei, const int* __restrict__ row_ptr, const int* __restrict__ col,
    const float* __restrict__ xl, const float* __restrict__ w1, const float* __restrict__ den1,
    const void* __restrict__ bias, const int* __restrict__ flags, float* __restrict__ hout)
{
  int i = blockIdx.x * 4 + (threadIdx.x >> 6);
  if (i >= N_NODES) return;
  int fB = flags[8];
  int lane = threadIdx.x & 63;
  int hh = lane >> 4;
  float dv = fin(den1[(size_t)i * 4 + hh]);
  float inv = 1.f / (dv + 1e-16f);
  int p0 = row_ptr[i], p1 = row_ptr[i + 1];
  float a0 = 0.f, a1 = 0.f;
  for (int j = p0; j < p1; j++) {
    int e = col[j]; if ((unsigned)e >= N_EDGES) e = 0;
    int s = ei[e];  if ((unsigned)s >= N_NODES) s = 0;
    float al = w1[(size_t)e * 4 + hh] * inv;
    float2 v = *(const float2*)(xl + (size_t)s * 128 + 2 * lane);
    a0 = fmaf(al, v.x, a0);
    a1 = fmaf(al, v.y, a1);
  }
  float o0 = fin(a0 + loadF(bias, fB, 2 * lane));
  float o1 = fin(a1 + loadF(bias, fB, 2 * lane + 1));
  o0 = o0 > 0.f ? o0 : __expf(o0) - 1.f;
  o1 = o1 > 0.f ? o1 : __expf(o1) - 1.f;
  *(float2*)(hout + (size_t)i * 128 + 2 * lane) = make_float2(o0, o1);
}

// ---------- layer-2 edge pass ----------
__global__ __launch_bounds__(256) void k_edge2(
    const void* __restrict__ ea, const int* __restrict__ ei,
    const float* __restrict__ xl, const float* __restrict__ xr,
    const void* __restrict__ We, const void* __restrict__ att,
    const int* __restrict__ flags,
    float* __restrict__ w2, float* __restrict__ den2)
{
  __shared__ unsigned short we[32 * 64];
  __shared__ float at[64];
  int fEA = flags[1], fWe = flags[13], fAtt = flags[14];
  int tid = threadIdx.x;
  if (fWe) {
    for (int i = tid * 8; i < 32 * 64; i += 2048) {
      float4 a = *(const float4*)((const float*)We + i);
      float4 b = *(const float4*)((const float*)We + i + 4);
      uint4 u;
      u.x = (unsigned)f2bf(a.x) | ((unsigned)f2bf(a.y) << 16);
      u.y = (unsigned)f2bf(a.z) | ((unsigned)f2bf(a.w) << 16);
      u.z = (unsigned)f2bf(b.x) | ((unsigned)f2bf(b.y) << 16);
      u.w = (unsigned)f2bf(b.z) | ((unsigned)f2bf(b.w) << 16);
      *(uint4*)(we + i) = u;
    }
  } else {
    for (int i = tid * 8; i < 32 * 64; i += 2048)
      *(uint4*)(we + i) = *(const uint4*)((const unsigned short*)We + i);
  }
  if (tid < 64) at[tid] = loadF(att, fAtt, tid);
  __syncthreads();
  int e = blockIdx.x * 4 + (tid >> 6);
  if (e >= N_EDGES) return;
  int lane = tid & 63;
  int s = ei[e], d = ei[N_EDGES + e];
  if ((unsigned)s >= N_NODES) s = 0;
  if ((unsigned)d >= N_NODES) d = 0;
  float eav = (lane < 32) ? loadF(ea, fEA, (size_t)e * 32 + lane) : 0.f;
  eav = fin(eav);
  float xlv = xl[(size_t)s * 64 + lane];
  float xrv = xr[(size_t)d * 64 + lane];
  float a = 0.f;
#pragma unroll
  for (int k = 0; k < 32; k++) {
    float av = __shfl(eav, k, 64);
    a = fmaf(av, bf2f(we[k * 64 + lane]), a);
  }
  float sv = xlv + xrv + a;
  float m = sv > 0.f ? sv : 0.2f * sv;
  float p = at[lane] * m;
  p += __shfl_xor(p, 1, 64);
  p += __shfl_xor(p, 2, 64);
  p += __shfl_xor(p, 4, 64);
  p += __shfl_xor(p, 8, 64);
  p += __shfl_xor(p, 16, 64);
  p += __shfl_xor(p, 32, 64);
  p = fin(p);
  float w = __expf(fminf(p, 25.f));
  if (lane == 0) {
    w2[e] = w;
    atomicAdd(&den2[d], w);
  }
}

// ---------- layer-2 aggregate -> out [N,64] (bf16 or f32 per flags[0]) ----------
__global__ __launch_bounds__(256) void k_agg2(
    const int* __restrict__ ei, const int* __restrict__ row_ptr, const int* __restrict__ col,
    const float* __restrict__ xl, const float* __restrict__ w2, const float* __restrict__ den2,
    const void* __restrict__ bias, const int* __restrict__ flags, void* __restrict__ out)
{
  int i = blockIdx.x * 4 + (threadIdx.x >> 6);
  if (i >= N_NODES) return;
  int fB = flags[15], fOut = flags[0];
  int lane = threadIdx.x & 63;
  float dv = fin(den2[i]);
  float inv = 1.f / (dv + 1e-16f);
  int p0 = row_ptr[i], p1 = row_ptr[i + 1];
  float a = 0.f;
  for (int j = p0; j < p1; j++) {
    int e = col[j]; if ((unsigned)e >= N_EDGES) e = 0;
    int s = ei[e];  if ((unsigned)s >= N_NODES) s = 0;
    a = fmaf(w2[e] * inv, xl[(size_t)s * 64 + lane], a);
  }
  float o = fin(a + loadF(bias, fB, lane));
  if (fOut) ((float*)out)[(size_t)i * 64 + lane] = o;
  else ((unsigned short*)out)[(size_t)i * 64 + lane] = f2bf(o);
}

extern "C" void kernel_launch(void* const* d_in, const int* in_sizes, int n_in,
                              void* d_out, int out_size, void* d_ws, size_t ws_size,
                              hipStream_t stream)
{
  (void)n_in; (void)out_size; (void)ws_size;
  const void* x    = d_in[0];
  const int*  ei   = (const int*)d_in[1];
  const void* ea   = d_in[2];
  const void* Wl1  = d_in[3];
  const void* bl1  = d_in[4];
  const void* Wr1  = d_in[5];
  const void* br1  = d_in[6];
  const void* We1  = d_in[7];
  const void* att1 = d_in[8];
  const void* bias1= d_in[9];
  const void* Wl2  = d_in[10];
  const void* bl2  = d_in[11];
  const void* Wr2  = d_in[12];
  const void* br2  = d_in[13];
  const void* We2  = d_in[14];
  const void* att2 = d_in[15];
  const void* bias2= d_in[16];

  char* ws = (char*)d_ws;
  size_t off = 0;
  auto take = [&](size_t bytes) -> char* {
    char* p = ws + off;
    off += (bytes + 255) & ~(size_t)255;
    return p;
  };
  float* xl1    = (float*)take((size_t)N_NODES * 128 * 4);
  float* xr1    = (float*)take((size_t)N_NODES * 128 * 4);
  float* hbuf   = (float*)take((size_t)N_NODES * 128 * 4);
  float* w1     = (float*)take((size_t)N_EDGES * 4 * 4);
  int*   counts = (int*)  take((size_t)N_NODES * 4);       // zero block start
  float* den1   = (float*)take((size_t)N_NODES * 4 * 4);
  float* den2   = (float*)take((size_t)N_NODES * 4);       // zero block end
  int*   row_ptr= (int*)  take((size_t)(N_NODES + 1) * 4);
  int*   cursor = (int*)  take((size_t)N_NODES * 4);
  int*   col    = (int*)  take((size_t)N_EDGES * 4);
  int*   bsum   = (int*)  take(64 * 4);
  int*   flags  = (int*)  take(64 * 4);
  float* xl2 = xl1;
  float* xr2 = xr1;
  float* w2  = w1;

  int zn = (int)(((char*)den2 + (size_t)N_NODES * 4 - (char*)counts) / 4);

  Ptrs tl;
  const int map[16] = {0, 2, 3, 4, 5, 6, 7, 8, 9, 10, 11, 12, 13, 14, 15, 16};
  for (int j = 0; j < 16; j++) { tl.p[j] = d_in[map[j]]; tl.n[j] = in_sizes[map[j]]; }

  int nb = (N_NODES + 1023) / 1024;
  k_detect<<<16, 256, 0, stream>>>(tl, flags);
  k_zero<<<(zn + 255) / 256, 256, 0, stream>>>(counts, zn);
  k_gemm1<<<dim3((N_NODES + 31) / 32, 2), 256, 0, stream>>>(x, Wl1, bl1, Wr1, br1, flags, xl1, xr1);
  k_hist<<<(N_EDGES + 255) / 256, 256, 0, stream>>>(ei, counts);
  k_scan1<<<nb, 256, 0, stream>>>(counts, row_ptr, bsum);
  k_scan2<<<1, 64, 0, stream>>>(bsum, nb);
  k_scan3<<<nb, 256, 0, stream>>>(row_ptr, cursor, bsum);
  k_scatter<<<(N_EDGES + 255) / 256, 256, 0, stream>>>(ei, cursor, col);
  k_edge1<<<(N_EDGES + 3) / 4, 256, 0, stream>>>(ea, ei, xl1, xr1, We1, att1, flags, w1, den1);
  k_agg1<<<(N_NODES + 3) / 4, 256, 0, stream>>>(ei, row_ptr, col, xl1, w1, den1, bias1, flags, hbuf);
  k_gemm2<<<dim3((N_NODES + 31) / 32, 2), 256, 0, stream>>>(hbuf, Wl2, bl2, Wr2, br2, flags, xl2, xr2);
  k_edge2<<<(N_EDGES + 3) / 4, 256, 0, stream>>>(ea, ei, xl2, xr2, We2, att2, flags, w2, den2);
  k_agg2<<<(N_NODES + 3) / 4, 256, 0, stream>>>(ei, row_ptr, col, xl2, w2, den2, bias2, flags, d_out);
}

// Round 3
// 1166.236 us; speedup vs baseline: 1.3069x; 1.3069x over previous
//
#include <hip/hip_runtime.h>
#include <stdint.h>

#define N_NODES 50000
#define N_EDGES 800000

// flag indices: 0:x 1:ea 2:Wl1 3:bl1 4:Wr1 5:br1 6:We1 7:att1 8:bias1
//               9:Wl2 10:bl2 11:Wr2 12:br2 13:We2 14:att2 15:bias2
struct Ptrs { const void* p[16]; int n[16]; };

__device__ __forceinline__ float bf2f(unsigned short u){
  union { unsigned int i; float f; } v; v.i = ((unsigned int)u) << 16; return v.f;
}
__device__ __forceinline__ float lo16(unsigned int u){ union { unsigned int i; float f; } v; v.i = u << 16; return v.f; }
__device__ __forceinline__ float hi16(unsigned int u){ union { unsigned int i; float f; } v; v.i = u & 0xffff0000u; return v.f; }
__device__ __forceinline__ unsigned short f2bf(float f){
  if (!(f == f)) return 0;
  unsigned int x = __float_as_uint(f);
  unsigned int r = (x + 0x7fffu + ((x >> 16) & 1u)) >> 16;
  return (unsigned short)r;
}
__device__ __forceinline__ float fin(float v){
  if (!(v == v)) return 0.f;
  return fminf(fmaxf(v, -1e30f), 1e30f);
}
__device__ __forceinline__ float loadF(const void* p, int f32, size_t idx){
  return f32 ? ((const float*)p)[idx] : bf2f(((const unsigned short*)p)[idx]);
}

// stage n bf16 elems of W (bf16 or f32 source) into LDS; n multiple of 2048
__device__ __forceinline__ void stageW(unsigned short* dst, const void* src, int n, int f32, int tid){
  if (f32) {
    for (int i = tid * 8; i < n; i += 2048) {
      float4 a = *(const float4*)((const float*)src + i);
      float4 b = *(const float4*)((const float*)src + i + 4);
      uint4 u;
      u.x = (unsigned)f2bf(a.x) | ((unsigned)f2bf(a.y) << 16);
      u.y = (unsigned)f2bf(a.z) | ((unsigned)f2bf(a.w) << 16);
      u.z = (unsigned)f2bf(b.x) | ((unsigned)f2bf(b.y) << 16);
      u.w = (unsigned)f2bf(b.z) | ((unsigned)f2bf(b.w) << 16);
      *(uint4*)(dst + i) = u;
    }
  } else {
    for (int i = tid * 8; i < n; i += 2048)
      *(uint4*)(dst + i) = *(const uint4*)((const unsigned short*)src + i);
  }
}

// ---------- dtype detect ----------
__global__ __launch_bounds__(256) void k_detect(Ptrs tl, int* __restrict__ flags)
{
  __shared__ int red[256];
  int b = blockIdx.x, t = threadIdx.x;
  const unsigned short* p = (const unsigned short*)tl.p[b];
  int n = tl.n[b]; if (n > 16384) n = 16384;
  int crazy = 0;
  for (int i = t; i < n; i += 256) {
    unsigned short u = p[i];
    if (u) {
      int ex = (u >> 7) & 0xFF;
      if (ex == 0xFF || ex < 0x60) crazy++;
    }
  }
  red[t] = crazy; __syncthreads();
  for (int off = 128; off; off >>= 1) { if (t < off) red[t] += red[t + off]; __syncthreads(); }
  if (t == 0) flags[b] = (red[0] * 10 > n) ? 1 : 0;
}

__global__ __launch_bounds__(256) void k_zero(int* __restrict__ p, int n)
{
  int i = blockIdx.x * 256 + threadIdx.x;
  if (i < n) p[i] = 0;
}

// ---------- ee GEMMs for BOTH layers: ee1[E,128] bf16, ee2[E,64] bf16 ----------
// block = 32 edges; thread (r=tid>>3, cg=tid&7) computes 16 ch of ee1 + 8 of ee2
__global__ __launch_bounds__(256) void k_ee(
    const void* __restrict__ ea, const void* __restrict__ We1, const void* __restrict__ We2,
    const int* __restrict__ flags,
    unsigned int* __restrict__ ee1u, unsigned int* __restrict__ ee2u)
{
  __shared__ unsigned short w1s[32 * 128];   // 8 KB
  __shared__ unsigned short w2s[32 * 64];    // 4 KB
  __shared__ unsigned short eas[32 * 33];    // padded stride 33 (conflict-free)
  int tid = threadIdx.x;
  stageW(w1s, We1, 4096, flags[6], tid);
  stageW(w2s, We2, 2048, flags[13], tid);
  int e0 = blockIdx.x * 32;
  {
    int i = tid * 4;                  // 1024 elems exactly
    int r = i >> 5, k = i & 31;
    if (flags[1]) {
      float4 v = *(const float4*)((const float*)ea + (size_t)(e0 + r) * 32 + k);
      eas[r * 33 + k]     = f2bf(v.x);
      eas[r * 33 + k + 1] = f2bf(v.y);
      eas[r * 33 + k + 2] = f2bf(v.z);
      eas[r * 33 + k + 3] = f2bf(v.w);
    } else {
      uint2 u = *(const uint2*)((const unsigned short*)ea + (size_t)(e0 + r) * 32 + k);
      eas[r * 33 + k]     = (unsigned short)(u.x & 0xffffu);
      eas[r * 33 + k + 1] = (unsigned short)(u.x >> 16);
      eas[r * 33 + k + 2] = (unsigned short)(u.y & 0xffffu);
      eas[r * 33 + k + 3] = (unsigned short)(u.y >> 16);
    }
  }
  __syncthreads();
  int r = tid >> 3, cg = tid & 7;
  float a1[16], a2[8];
#pragma unroll
  for (int j = 0; j < 16; j++) a1[j] = 0.f;
#pragma unroll
  for (int j = 0; j < 8; j++) a2[j] = 0.f;
  const unsigned int* w1p = (const unsigned int*)w1s;   // [k][64 pairs]
  const unsigned int* w2p = (const unsigned int*)w2s;   // [k][32 pairs]
#pragma unroll 2
  for (int k = 0; k < 32; k++) {
    float av = bf2f(eas[r * 33 + k]);
    uint4 q0 = *(const uint4*)(w1p + k * 64 + cg * 4);
    uint4 q1 = *(const uint4*)(w1p + k * 64 + 32 + cg * 4);
    uint4 q2 = *(const uint4*)(w2p + k * 32 + cg * 4);
    a1[0]  = fmaf(av, lo16(q0.x), a1[0]);  a1[1]  = fmaf(av, hi16(q0.x), a1[1]);
    a1[2]  = fmaf(av, lo16(q0.y), a1[2]);  a1[3]  = fmaf(av, hi16(q0.y), a1[3]);
    a1[4]  = fmaf(av, lo16(q0.z), a1[4]);  a1[5]  = fmaf(av, hi16(q0.z), a1[5]);
    a1[6]  = fmaf(av, lo16(q0.w), a1[6]);  a1[7]  = fmaf(av, hi16(q0.w), a1[7]);
    a1[8]  = fmaf(av, lo16(q1.x), a1[8]);  a1[9]  = fmaf(av, hi16(q1.x), a1[9]);
    a1[10] = fmaf(av, lo16(q1.y), a1[10]); a1[11] = fmaf(av, hi16(q1.y), a1[11]);
    a1[12] = fmaf(av, lo16(q1.z), a1[12]); a1[13] = fmaf(av, hi16(q1.z), a1[13]);
    a1[14] = fmaf(av, lo16(q1.w), a1[14]); a1[15] = fmaf(av, hi16(q1.w), a1[15]);
    a2[0]  = fmaf(av, lo16(q2.x), a2[0]);  a2[1]  = fmaf(av, hi16(q2.x), a2[1]);
    a2[2]  = fmaf(av, lo16(q2.y), a2[2]);  a2[3]  = fmaf(av, hi16(q2.y), a2[3]);
    a2[4]  = fmaf(av, lo16(q2.z), a2[4]);  a2[5]  = fmaf(av, hi16(q2.z), a2[5]);
    a2[6]  = fmaf(av, lo16(q2.w), a2[6]);  a2[7]  = fmaf(av, hi16(q2.w), a2[7]);
  }
  size_t e = (size_t)(e0 + r);
  uint4 o;
  o.x = (unsigned)f2bf(a1[0]) | ((unsigned)f2bf(a1[1]) << 16);
  o.y = (unsigned)f2bf(a1[2]) | ((unsigned)f2bf(a1[3]) << 16);
  o.z = (unsigned)f2bf(a1[4]) | ((unsigned)f2bf(a1[5]) << 16);
  o.w = (unsigned)f2bf(a1[6]) | ((unsigned)f2bf(a1[7]) << 16);
  *(uint4*)(ee1u + e * 64 + cg * 4) = o;
  o.x = (unsigned)f2bf(a1[8])  | ((unsigned)f2bf(a1[9])  << 16);
  o.y = (unsigned)f2bf(a1[10]) | ((unsigned)f2bf(a1[11]) << 16);
  o.z = (unsigned)f2bf(a1[12]) | ((unsigned)f2bf(a1[13]) << 16);
  o.w = (unsigned)f2bf(a1[14]) | ((unsigned)f2bf(a1[15]) << 16);
  *(uint4*)(ee1u + e * 64 + 32 + cg * 4) = o;
  o.x = (unsigned)f2bf(a2[0]) | ((unsigned)f2bf(a2[1]) << 16);
  o.y = (unsigned)f2bf(a2[2]) | ((unsigned)f2bf(a2[3]) << 16);
  o.z = (unsigned)f2bf(a2[4]) | ((unsigned)f2bf(a2[5]) << 16);
  o.w = (unsigned)f2bf(a2[6]) | ((unsigned)f2bf(a2[7]) << 16);
  *(uint4*)(ee2u + e * 32 + cg * 4) = o;
}

// ---------- layer-1 GEMM: xl/xr = x@W + b  [N,128]x[128,128] ----------
__global__ __launch_bounds__(256) void k_gemm1(
    const void* __restrict__ x,
    const void* __restrict__ Wl, const void* __restrict__ bl,
    const void* __restrict__ Wr, const void* __restrict__ br,
    const int* __restrict__ flags,
    float* __restrict__ xl, float* __restrict__ xr)
{
  __shared__ float xs[32 * 132];
  __shared__ unsigned short ws[128 * 128];
  const void* W  = blockIdx.y ? Wr : Wl;
  const void* bb = blockIdx.y ? br : bl;
  int fW = blockIdx.y ? flags[4] : flags[2];
  int fB = blockIdx.y ? flags[5] : flags[3];
  int fX = flags[0];
  float* out = blockIdx.y ? xr : xl;
  int tid = threadIdx.x;
  int row0 = blockIdx.x * 32;
  stageW(ws, W, 128 * 128, fW, tid);
  for (int i = tid * 4; i < 32 * 128; i += 1024) {
    int r = i >> 7, k = i & 127;
    int row = row0 + r;
    float4 v = make_float4(0.f, 0.f, 0.f, 0.f);
    if (row < N_NODES) {
      if (fX) v = *(const float4*)((const float*)x + (size_t)row * 128 + k);
      else {
        uint2 u = *(const uint2*)((const unsigned short*)x + (size_t)row * 128 + k);
        v.x = lo16(u.x); v.y = hi16(u.x); v.z = lo16(u.y); v.w = hi16(u.y);
      }
    }
    *(float4*)(xs + r * 132 + k) = v;
  }
  __syncthreads();
  int r = tid >> 3, cg = tid & 7;
  float acc[16];
#pragma unroll
  for (int j = 0; j < 16; j++) acc[j] = 0.f;
#pragma unroll 4
  for (int k = 0; k < 128; k++) {
    float xv = xs[r * 132 + k];
    uint4 p0 = *(const uint4*)(ws + k * 128 + cg * 8);
    uint4 p1 = *(const uint4*)(ws + k * 128 + 64 + cg * 8);
    acc[0]  = fmaf(xv, lo16(p0.x), acc[0]);  acc[1]  = fmaf(xv, hi16(p0.x), acc[1]);
    acc[2]  = fmaf(xv, lo16(p0.y), acc[2]);  acc[3]  = fmaf(xv, hi16(p0.y), acc[3]);
    acc[4]  = fmaf(xv, lo16(p0.z), acc[4]);  acc[5]  = fmaf(xv, hi16(p0.z), acc[5]);
    acc[6]  = fmaf(xv, lo16(p0.w), acc[6]);  acc[7]  = fmaf(xv, hi16(p0.w), acc[7]);
    acc[8]  = fmaf(xv, lo16(p1.x), acc[8]);  acc[9]  = fmaf(xv, hi16(p1.x), acc[9]);
    acc[10] = fmaf(xv, lo16(p1.y), acc[10]); acc[11] = fmaf(xv, hi16(p1.y), acc[11]);
    acc[12] = fmaf(xv, lo16(p1.z), acc[12]); acc[13] = fmaf(xv, hi16(p1.z), acc[13]);
    acc[14] = fmaf(xv, lo16(p1.w), acc[14]); acc[15] = fmaf(xv, hi16(p1.w), acc[15]);
  }
  int row = row0 + r;
  if (row < N_NODES) {
    float* op = out + (size_t)row * 128;
#pragma unroll
    for (int j = 0; j < 8; j++) op[cg * 8 + j]      = fin(acc[j]     + loadF(bb, fB, cg * 8 + j));
#pragma unroll
    for (int j = 0; j < 8; j++) op[64 + cg * 8 + j] = fin(acc[8 + j] + loadF(bb, fB, 64 + cg * 8 + j));
  }
}

// ---------- layer-2 GEMM: xl2/xr2 = h@W + b  [N,128]x[128,64] ----------
__global__ __launch_bounds__(256) void k_gemm2(
    const float* __restrict__ h,
    const void* __restrict__ Wl, const void* __restrict__ bl,
    const void* __restrict__ Wr, const void* __restrict__ br,
    const int* __restrict__ flags,
    float* __restrict__ xl, float* __restrict__ xr)
{
  __shared__ float hs[32 * 132];
  __shared__ unsigned short ws[128 * 64];
  const void* W  = blockIdx.y ? Wr : Wl;
  const void* bb = blockIdx.y ? br : bl;
  int fW = blockIdx.y ? flags[11] : flags[9];
  int fB = blockIdx.y ? flags[12] : flags[10];
  float* out = blockIdx.y ? xr : xl;
  int tid = threadIdx.x;
  int row0 = blockIdx.x * 32;
  stageW(ws, W, 128 * 64, fW, tid);
  for (int i = tid * 4; i < 32 * 128; i += 1024) {
    int r = i >> 7, k = i & 127;
    int row = row0 + r;
    float4 v = make_float4(0.f, 0.f, 0.f, 0.f);
    if (row < N_NODES) v = *(const float4*)(h + (size_t)row * 128 + k);
    *(float4*)(hs + r * 132 + k) = v;
  }
  __syncthreads();
  int r = tid >> 3, cg = tid & 7;
  float acc[8];
#pragma unroll
  for (int j = 0; j < 8; j++) acc[j] = 0.f;
#pragma unroll 4
  for (int k = 0; k < 128; k++) {
    float hv = hs[r * 132 + k];
    uint4 p = *(const uint4*)(ws + k * 64 + cg * 8);
    acc[0] = fmaf(hv, lo16(p.x), acc[0]); acc[1] = fmaf(hv, hi16(p.x), acc[1]);
    acc[2] = fmaf(hv, lo16(p.y), acc[2]); acc[3] = fmaf(hv, hi16(p.y), acc[3]);
    acc[4] = fmaf(hv, lo16(p.z), acc[4]); acc[5] = fmaf(hv, hi16(p.z), acc[5]);
    acc[6] = fmaf(hv, lo16(p.w), acc[6]); acc[7] = fmaf(hv, hi16(p.w), acc[7]);
  }
  int row = row0 + r;
  if (row < N_NODES) {
    float* op = out + (size_t)row * 64;
#pragma unroll
    for (int j = 0; j < 8; j++) op[cg * 8 + j] = fin(acc[j] + loadF(bb, fB, cg * 8 + j));
  }
}

// ---------- CSR build ----------
__global__ __launch_bounds__(256) void k_hist(const int* __restrict__ ei, int* __restrict__ counts)
{
  int e = blockIdx.x * 256 + threadIdx.x;
  if (e < N_EDGES) {
    int d = ei[N_EDGES + e]; if ((unsigned)d >= N_NODES) d = 0;
    atomicAdd(&counts[d], 1);
  }
}

__global__ __launch_bounds__(256) void k_scan1(const int* __restrict__ counts,
                                               int* __restrict__ row_ptr, int* __restrict__ bsum)
{
  __shared__ int lds[256];
  int t = threadIdx.x;
  int base = blockIdx.x * 1024 + t * 4;
  int c0 = (base + 0) < N_NODES ? counts[base + 0] : 0;
  int c1 = (base + 1) < N_NODES ? counts[base + 1] : 0;
  int c2 = (base + 2) < N_NODES ? counts[base + 2] : 0;
  int c3 = (base + 3) < N_NODES ? counts[base + 3] : 0;
  int s = c0 + c1 + c2 + c3;
  lds[t] = s; __syncthreads();
  for (int off = 1; off < 256; off <<= 1) {
    int v = (t >= off) ? lds[t - off] : 0;
    __syncthreads();
    lds[t] += v;
    __syncthreads();
  }
  int incl = lds[t];
  int excl = incl - s;
  if (base + 0 < N_NODES) row_ptr[base + 0] = excl;
  if (base + 1 < N_NODES) row_ptr[base + 1] = excl + c0;
  if (base + 2 < N_NODES) row_ptr[base + 2] = excl + c0 + c1;
  if (base + 3 < N_NODES) row_ptr[base + 3] = excl + c0 + c1 + c2;
  if (t == 255) bsum[blockIdx.x] = incl;
}

__global__ __launch_bounds__(64) void k_scan2(int* __restrict__ bsum, int nb)
{
  __shared__ int l[64];
  int t = threadIdx.x;
  if (t < nb) l[t] = bsum[t];
  __syncthreads();
  if (t == 0) { int run = 0; for (int i = 0; i < nb; i++) { int v = l[i]; l[i] = run; run += v; } }
  __syncthreads();
  if (t < nb) bsum[t] = l[t];
}

__global__ __launch_bounds__(256) void k_scan3(int* __restrict__ row_ptr, int* __restrict__ cursor,
                                               const int* __restrict__ bsum)
{
  int t = threadIdx.x;
  int base = blockIdx.x * 1024 + t * 4;
  int add = bsum[blockIdx.x];
#pragma unroll
  for (int j = 0; j < 4; j++) {
    int i = base + j;
    if (i < N_NODES) { int v = row_ptr[i] + add; row_ptr[i] = v; cursor[i] = v; }
  }
  if (blockIdx.x == 0 && t == 0) row_ptr[N_NODES] = N_EDGES;
}

__global__ __launch_bounds__(256) void k_scatter(const int* __restrict__ ei,
                                                 int* __restrict__ cursor, int* __restrict__ col)
{
  int e = blockIdx.x * 256 + threadIdx.x;
  if (e < N_EDGES) {
    int d = ei[N_EDGES + e]; if ((unsigned)d >= N_NODES) d = 0;
    int p = atomicAdd(&cursor[d], 1);
    if ((unsigned)p < N_EDGES) col[p] = e;
  }
}

// ---------- fused layer-1: per-node edge scores + softmax + aggregate + ELU ----------
// wave per node; lane holds channels 2*lane, 2*lane+1; heads = 16-lane groups
__global__ __launch_bounds__(256) void k_fused1(
    const int* __restrict__ ei, const int* __restrict__ row_ptr, const int* __restrict__ col,
    const float* __restrict__ xl, const float* __restrict__ xr,
    const unsigned int* __restrict__ ee1u,
    const void* __restrict__ ea, const void* __restrict__ We,
    const void* __restrict__ att, const void* __restrict__ bias,
    const int* __restrict__ flags, int use_ee,
    float* __restrict__ hout)
{
  __shared__ unsigned short wes[32 * 128];   // used only in fallback
  __shared__ float at[128];
  int tid = threadIdx.x;
  if (!use_ee) stageW(wes, We, 4096, flags[6], tid);
  if (tid < 128) at[tid] = loadF(att, flags[7], tid);
  __syncthreads();
  int i = blockIdx.x * 4 + (tid >> 6);       // grid exact: 50000/4
  int lane = tid & 63;
  float at0 = at[2 * lane], at1 = at[2 * lane + 1];
  float2 xrv = *(const float2*)(xr + (size_t)i * 128 + 2 * lane);
  int p0 = row_ptr[i], p1 = row_ptr[i + 1];
  float acc0 = 0.f, acc1 = 0.f, den = 0.f;
  int fEA = flags[1];
  const unsigned int* wep = (const unsigned int*)wes;
  for (int j = p0; j < p1; j++) {
    int e = col[j];
    int s = ei[e];
    float2 xlv = *(const float2*)(xl + (size_t)s * 128 + 2 * lane);
    float e0, e1;
    if (use_ee) {
      unsigned int u = ee1u[(size_t)e * 64 + lane];
      e0 = lo16(u); e1 = hi16(u);
    } else {
      float eav = (lane < 32) ? loadF(ea, fEA, (size_t)e * 32 + lane) : 0.f;
      e0 = 0.f; e1 = 0.f;
#pragma unroll
      for (int k = 0; k < 32; k++) {
        float av = __shfl(eav, k, 64);
        unsigned int p = wep[k * 64 + lane];
        e0 = fmaf(av, lo16(p), e0);
        e1 = fmaf(av, hi16(p), e1);
      }
    }
    float m0 = xlv.x + xrv.x + e0;
    float m1 = xlv.y + xrv.y + e1;
    m0 = m0 > 0.f ? m0 : 0.2f * m0;
    m1 = m1 > 0.f ? m1 : 0.2f * m1;
    float pl = fmaf(at0, m0, at1 * m1);
    pl += __shfl_xor(pl, 1, 64);
    pl += __shfl_xor(pl, 2, 64);
    pl += __shfl_xor(pl, 4, 64);
    pl += __shfl_xor(pl, 8, 64);
    float w = __expf(fminf(pl, 25.f));
    acc0 = fmaf(w, xlv.x, acc0);
    acc1 = fmaf(w, xlv.y, acc1);
    den += w;
  }
  float inv = 1.f / (den + 1e-16f);
  float o0 = fin(fmaf(acc0, inv, loadF(bias, flags[8], 2 * lane)));
  float o1 = fin(fmaf(acc1, inv, loadF(bias, flags[8], 2 * lane + 1)));
  o0 = o0 > 0.f ? o0 : __expf(o0) - 1.f;
  o1 = o1 > 0.f ? o1 : __expf(o1) - 1.f;
  *(float2*)(hout + (size_t)i * 128 + 2 * lane) = make_float2(o0, o1);
}

// ---------- fused layer-2: H=1, C=64, lane = channel; write final out ----------
__global__ __launch_bounds__(256) void k_fused2(
    const int* __restrict__ ei, const int* __restrict__ row_ptr, const int* __restrict__ col,
    const float* __restrict__ xl, const float* __restrict__ xr,
    const unsigned int* __restrict__ ee2u,
    const void* __restrict__ ea, const void* __restrict__ We,
    const void* __restrict__ att, const void* __restrict__ bias,
    const int* __restrict__ flags, int use_ee,
    void* __restrict__ out)
{
  __shared__ unsigned short wes[32 * 64];
  __shared__ float at[64];
  int tid = threadIdx.x;
  if (!use_ee) stageW(wes, We, 2048, flags[13], tid);
  if (tid < 64) at[tid] = loadF(att, flags[14], tid);
  __syncthreads();
  int i = blockIdx.x * 4 + (tid >> 6);
  int lane = tid & 63;
  float atv = at[lane];
  float xrv = xr[(size_t)i * 64 + lane];
  int p0 = row_ptr[i], p1 = row_ptr[i + 1];
  float acc = 0.f, den = 0.f;
  int fEA = flags[1];
  const unsigned short* ee2s = (const unsigned short*)ee2u;
  for (int j = p0; j < p1; j++) {
    int e = col[j];
    int s = ei[e];
    float xlv = xl[(size_t)s * 64 + lane];
    float ee;
    if (use_ee) {
      ee = bf2f(ee2s[(size_t)e * 64 + lane]);
    } else {
      float eav = (lane < 32) ? loadF(ea, fEA, (size_t)e * 32 + lane) : 0.f;
      ee = 0.f;
#pragma unroll
      for (int k = 0; k < 32; k++) {
        float av = __shfl(eav, k, 64);
        ee = fmaf(av, bf2f(wes[k * 64 + lane]), ee);
      }
    }
    float m = xlv + xrv + ee;
    m = m > 0.f ? m : 0.2f * m;
    float pl = atv * m;
    pl += __shfl_xor(pl, 1, 64);
    pl += __shfl_xor(pl, 2, 64);
    pl += __shfl_xor(pl, 4, 64);
    pl += __shfl_xor(pl, 8, 64);
    pl += __shfl_xor(pl, 16, 64);
    pl += __shfl_xor(pl, 32, 64);
    float w = __expf(fminf(pl, 25.f));
    acc = fmaf(w, xlv, acc);
    den += w;
  }
  float inv = 1.f / (den + 1e-16f);
  float o = fin(fmaf(acc, inv, loadF(bias, flags[15], lane)));
  if (flags[0]) ((float*)out)[(size_t)i * 64 + lane] = o;
  else ((unsigned short*)out)[(size_t)i * 64 + lane] = f2bf(o);
}

extern "C" void kernel_launch(void* const* d_in, const int* in_sizes, int n_in,
                              void* d_out, int out_size, void* d_ws, size_t ws_size,
                              hipStream_t stream)
{
  (void)n_in; (void)out_size;
  const void* x    = d_in[0];
  const int*  ei   = (const int*)d_in[1];
  const void* ea   = d_in[2];
  const void* Wl1  = d_in[3];
  const void* bl1  = d_in[4];
  const void* Wr1  = d_in[5];
  const void* br1  = d_in[6];
  const void* We1  = d_in[7];
  const void* att1 = d_in[8];
  const void* bias1= d_in[9];
  const void* Wl2  = d_in[10];
  const void* bl2  = d_in[11];
  const void* Wr2  = d_in[12];
  const void* br2  = d_in[13];
  const void* We2  = d_in[14];
  const void* att2 = d_in[15];
  const void* bias2= d_in[16];

  char* ws = (char*)d_ws;
  size_t off = 0;
  auto take = [&](size_t bytes) -> char* {
    char* p = ws + off;
    off += (bytes + 255) & ~(size_t)255;
    return p;
  };
  float* xl1    = (float*)take((size_t)N_NODES * 128 * 4);
  float* xr1    = (float*)take((size_t)N_NODES * 128 * 4);
  float* hbuf   = (float*)take((size_t)N_NODES * 128 * 4);
  int*   counts = (int*)  take((size_t)N_NODES * 4);
  int*   row_ptr= (int*)  take((size_t)(N_NODES + 1) * 4);
  int*   cursor = (int*)  take((size_t)N_NODES * 4);
  int*   col    = (int*)  take((size_t)N_EDGES * 4);
  int*   bsum   = (int*)  take(64 * 4);
  int*   flags  = (int*)  take(64 * 4);
  size_t base_end = off;
  unsigned int* ee1u = (unsigned int*)take((size_t)N_EDGES * 64 * 4);  // 204.8 MB
  unsigned int* ee2u = (unsigned int*)take((size_t)N_EDGES * 32 * 4);  // 102.4 MB
  int use_ee = (off <= ws_size) ? 1 : 0;
  if (!use_ee) { ee1u = (unsigned int*)(ws + base_end); ee2u = ee1u; }  // unused
  float* xl2 = xl1;   // layer-2 transforms reuse layer-1 space (N*64 <= N*128)
  float* xr2 = xr1;

  Ptrs tl;
  const int map[16] = {0, 2, 3, 4, 5, 6, 7, 8, 9, 10, 11, 12, 13, 14, 15, 16};
  for (int j = 0; j < 16; j++) { tl.p[j] = d_in[map[j]]; tl.n[j] = in_sizes[map[j]]; }

  int nb = (N_NODES + 1023) / 1024;
  k_detect<<<16, 256, 0, stream>>>(tl, flags);
  k_zero<<<(N_NODES + 255) / 256, 256, 0, stream>>>(counts, N_NODES);
  if (use_ee)
    k_ee<<<N_EDGES / 32, 256, 0, stream>>>(ea, We1, We2, flags, ee1u, ee2u);
  k_gemm1<<<dim3((N_NODES + 31) / 32, 2), 256, 0, stream>>>(x, Wl1, bl1, Wr1, br1, flags, xl1, xr1);
  k_hist<<<(N_EDGES + 255) / 256, 256, 0, stream>>>(ei, counts);
  k_scan1<<<nb, 256, 0, stream>>>(counts, row_ptr, bsum);
  k_scan2<<<1, 64, 0, stream>>>(bsum, nb);
  k_scan3<<<nb, 256, 0, stream>>>(row_ptr, cursor, bsum);
  k_scatter<<<(N_EDGES + 255) / 256, 256, 0, stream>>>(ei, cursor, col);
  k_fused1<<<N_NODES / 4, 256, 0, stream>>>(ei, row_ptr, col, xl1, xr1, ee1u,
                                            ea, We1, att1, bias1, flags, use_ee, hbuf);
  k_gemm2<<<dim3((N_NODES + 31) / 32, 2), 256, 0, stream>>>(hbuf, Wl2, bl2, Wr2, br2, flags, xl2, xr2);
  k_fused2<<<N_NODES / 4, 256, 0, stream>>>(ei, row_ptr, col, xl2, xr2, ee2u,
                                            ea, We2, att2, bias2, flags, use_ee, d_out);
}

// Round 4
// 997.267 us; speedup vs baseline: 1.5283x; 1.1694x over previous
//
#include <hip/hip_runtime.h>
#include <stdint.h>

#define N_NODES 50000
#define N_EDGES 800000

// flag indices: 0:x 1:ea 2:Wl1 3:bl1 4:Wr1 5:br1 6:We1 7:att1 8:bias1
//               9:Wl2 10:bl2 11:Wr2 12:br2 13:We2 14:att2 15:bias2
struct Ptrs { const void* p[16]; int n[16]; };

typedef __attribute__((ext_vector_type(8))) short bf16x8;
typedef __attribute__((ext_vector_type(4))) float f32x4;

__device__ __forceinline__ float bf2f(unsigned short u){
  union { unsigned int i; float f; } v; v.i = ((unsigned int)u) << 16; return v.f;
}
__device__ __forceinline__ float lo16(unsigned int u){ union { unsigned int i; float f; } v; v.i = u << 16; return v.f; }
__device__ __forceinline__ float hi16(unsigned int u){ union { unsigned int i; float f; } v; v.i = u & 0xffff0000u; return v.f; }
__device__ __forceinline__ unsigned short f2bf(float f){
  if (!(f == f)) return 0;
  unsigned int x = __float_as_uint(f);
  unsigned int r = (x + 0x7fffu + ((x >> 16) & 1u)) >> 16;
  return (unsigned short)r;
}
__device__ __forceinline__ float fin(float v){
  if (!(v == v)) return 0.f;
  return fminf(fmaxf(v, -1e30f), 1e30f);
}
__device__ __forceinline__ float loadF(const void* p, int f32, size_t idx){
  return f32 ? ((const float*)p)[idx] : bf2f(((const unsigned short*)p)[idx]);
}

// stage n bf16 elems of W (bf16 or f32 source) into LDS; n multiple of 2048
__device__ __forceinline__ void stageW(unsigned short* dst, const void* src, int n, int f32, int tid){
  if (f32) {
    for (int i = tid * 8; i < n; i += 2048) {
      float4 a = *(const float4*)((const float*)src + i);
      float4 b = *(const float4*)((const float*)src + i + 4);
      uint4 u;
      u.x = (unsigned)f2bf(a.x) | ((unsigned)f2bf(a.y) << 16);
      u.y = (unsigned)f2bf(a.z) | ((unsigned)f2bf(a.w) << 16);
      u.z = (unsigned)f2bf(b.x) | ((unsigned)f2bf(b.y) << 16);
      u.w = (unsigned)f2bf(b.z) | ((unsigned)f2bf(b.w) << 16);
      *(uint4*)(dst + i) = u;
    }
  } else {
    for (int i = tid * 8; i < n; i += 2048)
      *(uint4*)(dst + i) = *(const uint4*)((const unsigned short*)src + i);
  }
}

// ---------- dtype detect ----------
__global__ __launch_bounds__(256) void k_detect(Ptrs tl, int* __restrict__ flags)
{
  __shared__ int red[256];
  int b = blockIdx.x, t = threadIdx.x;
  const unsigned short* p = (const unsigned short*)tl.p[b];
  int n = tl.n[b]; if (n > 16384) n = 16384;
  int crazy = 0;
  for (int i = t; i < n; i += 256) {
    unsigned short u = p[i];
    if (u) {
      int ex = (u >> 7) & 0xFF;
      if (ex == 0xFF || ex < 0x60) crazy++;
    }
  }
  red[t] = crazy; __syncthreads();
  for (int off = 128; off; off >>= 1) { if (t < off) red[t] += red[t + off]; __syncthreads(); }
  if (t == 0) flags[b] = (red[0] * 10 > n) ? 1 : 0;
}

__global__ __launch_bounds__(256) void k_zero(int* __restrict__ p, int n)
{
  int i = blockIdx.x * 256 + threadIdx.x;
  if (i < n) p[i] = 0;
}

// ---------- MFMA ee GEMM: ee1[E,128] bf16, ee2[E,64] bf16  (ea[E,32] @ We[32,·]) ----------
// block = 64 edges (4 waves x 16); 12 channel-tiles of 16 via mfma_f32_16x16x32_bf16.
// D[ch][edge]: A = WeT tile (m=ch,k), B = ea^T (k, n=edge).
__global__ __launch_bounds__(256) void k_ee_mfma(
    const void* __restrict__ ea, const void* __restrict__ We1, const void* __restrict__ We2,
    const int* __restrict__ flags,
    unsigned int* __restrict__ ee1u, unsigned int* __restrict__ ee2u)
{
  __shared__ unsigned short wt[192 * 32];     // WeT[ch][k]; ch 0..127 = We1, 128..191 = We2
  __shared__ unsigned short eas[64 * 40];     // ea tile [edge][k], stride 40 (2-way only)
  __shared__ unsigned short outs[64 * 200];   // [edge][ch], stride 200
  int tid = threadIdx.x;
  {
    int f = flags[6];
    for (int i = tid; i < 4096; i += 256) {            // We1[k][c] -> wt[c*32+k]
      int k = i >> 7, c = i & 127;
      wt[c * 32 + k] = f ? f2bf(((const float*)We1)[i]) : ((const unsigned short*)We1)[i];
    }
    f = flags[13];
    for (int i = tid; i < 2048; i += 256) {            // We2[k][c] -> wt[(128+c)*32+k]
      int k = i >> 6, c = i & 63;
      wt[(128 + c) * 32 + k] = f ? f2bf(((const float*)We2)[i]) : ((const unsigned short*)We2)[i];
    }
  }
  size_t e0 = (size_t)blockIdx.x * 64;
  if (flags[1]) {
    for (int i = tid * 4; i < 2048; i += 1024) {
      int r = i >> 5, k = i & 31;
      float4 v = *(const float4*)((const float*)ea + e0 * 32 + i);
      unsigned short* dp = eas + r * 40 + k;
      dp[0] = f2bf(v.x); dp[1] = f2bf(v.y); dp[2] = f2bf(v.z); dp[3] = f2bf(v.w);
    }
  } else {
    for (int i = tid * 4; i < 2048; i += 1024) {
      int r = i >> 5, k = i & 31;
      *(uint2*)(eas + r * 40 + k) = *(const uint2*)((const unsigned short*)ea + e0 * 32 + i);
    }
  }
  __syncthreads();
  int wv = tid >> 6, lane = tid & 63;
  int idx16 = lane & 15, quad = lane >> 4;
  int el = wv * 16;                                    // wave's local edge base
  bf16x8 bfrag = *(const bf16x8*)(eas + (el + idx16) * 40 + quad * 8);
#pragma unroll
  for (int t = 0; t < 12; t++) {
    bf16x8 afrag = *(const bf16x8*)(wt + (t * 16 + idx16) * 32 + quad * 8);
    f32x4 c = {0.f, 0.f, 0.f, 0.f};
    c = __builtin_amdgcn_mfma_f32_16x16x32_bf16(afrag, bfrag, c, 0, 0, 0);
    // lane holds D[ch = t*16 + quad*4 + r][edge = el + idx16]
    unsigned int u0 = (unsigned)f2bf(c[0]) | ((unsigned)f2bf(c[1]) << 16);
    unsigned int u1 = (unsigned)f2bf(c[2]) | ((unsigned)f2bf(c[3]) << 16);
    *(uint2*)(outs + (el + idx16) * 200 + t * 16 + quad * 4) = make_uint2(u0, u1);
  }
  // wave-local readback (same wave wrote these rows) -> coalesced stores
#pragma unroll
  for (int r = 0; r < 4; r++) {
    int e = el + (lane >> 4) + r * 4;
    uint4 v = *(const uint4*)(outs + e * 200 + (lane & 15) * 8);
    *(uint4*)(ee1u + (e0 + e) * 64 + (lane & 15) * 4) = v;
  }
#pragma unroll
  for (int r = 0; r < 2; r++) {
    int e = el + (lane >> 3) + r * 8;
    uint4 v = *(const uint4*)(outs + e * 200 + 128 + (lane & 7) * 8);
    *(uint4*)(ee2u + (e0 + e) * 32 + (lane & 7) * 4) = v;
  }
}

// ---------- layer-1 GEMM: xl(packed bf16) / xr(f32) = x@W + b ----------
__global__ __launch_bounds__(256) void k_gemm1(
    const void* __restrict__ x,
    const void* __restrict__ Wl, const void* __restrict__ bl,
    const void* __restrict__ Wr, const void* __restrict__ br,
    const int* __restrict__ flags,
    unsigned int* __restrict__ xlp, float* __restrict__ xr)
{
  __shared__ float xs[32 * 132];
  __shared__ unsigned short ws[128 * 128];
  const void* W  = blockIdx.y ? Wr : Wl;
  const void* bb = blockIdx.y ? br : bl;
  int fW = blockIdx.y ? flags[4] : flags[2];
  int fB = blockIdx.y ? flags[5] : flags[3];
  int fX = flags[0];
  int tid = threadIdx.x;
  int row0 = blockIdx.x * 32;
  stageW(ws, W, 128 * 128, fW, tid);
  for (int i = tid * 4; i < 32 * 128; i += 1024) {
    int r = i >> 7, k = i & 127;
    int row = row0 + r;
    float4 v = make_float4(0.f, 0.f, 0.f, 0.f);
    if (row < N_NODES) {
      if (fX) v = *(const float4*)((const float*)x + (size_t)row * 128 + k);
      else {
        uint2 u = *(const uint2*)((const unsigned short*)x + (size_t)row * 128 + k);
        v.x = lo16(u.x); v.y = hi16(u.x); v.z = lo16(u.y); v.w = hi16(u.y);
      }
    }
    *(float4*)(xs + r * 132 + k) = v;
  }
  __syncthreads();
  int r = tid >> 3, cg = tid & 7;
  float acc[16];
#pragma unroll
  for (int j = 0; j < 16; j++) acc[j] = 0.f;
#pragma unroll 4
  for (int k = 0; k < 128; k++) {
    float xv = xs[r * 132 + k];
    uint4 p0 = *(const uint4*)(ws + k * 128 + cg * 8);
    uint4 p1 = *(const uint4*)(ws + k * 128 + 64 + cg * 8);
    acc[0]  = fmaf(xv, lo16(p0.x), acc[0]);  acc[1]  = fmaf(xv, hi16(p0.x), acc[1]);
    acc[2]  = fmaf(xv, lo16(p0.y), acc[2]);  acc[3]  = fmaf(xv, hi16(p0.y), acc[3]);
    acc[4]  = fmaf(xv, lo16(p0.z), acc[4]);  acc[5]  = fmaf(xv, hi16(p0.z), acc[5]);
    acc[6]  = fmaf(xv, lo16(p0.w), acc[6]);  acc[7]  = fmaf(xv, hi16(p0.w), acc[7]);
    acc[8]  = fmaf(xv, lo16(p1.x), acc[8]);  acc[9]  = fmaf(xv, hi16(p1.x), acc[9]);
    acc[10] = fmaf(xv, lo16(p1.y), acc[10]); acc[11] = fmaf(xv, hi16(p1.y), acc[11]);
    acc[12] = fmaf(xv, lo16(p1.z), acc[12]); acc[13] = fmaf(xv, hi16(p1.z), acc[13]);
    acc[14] = fmaf(xv, lo16(p1.w), acc[14]); acc[15] = fmaf(xv, hi16(p1.w), acc[15]);
  }
  int row = row0 + r;
  if (row < N_NODES) {
    if (blockIdx.y == 0) {        // xl packed bf16 pairs: uint[N][64]
      unsigned int* op = xlp + (size_t)row * 64;
      uint4 o;
      unsigned int* ou = (unsigned int*)&o;
#pragma unroll
      for (int t = 0; t < 4; t++) {
        float f0 = fin(acc[2 * t]     + loadF(bb, fB, cg * 8 + 2 * t));
        float f1 = fin(acc[2 * t + 1] + loadF(bb, fB, cg * 8 + 2 * t + 1));
        ou[t] = (unsigned)f2bf(f0) | ((unsigned)f2bf(f1) << 16);
      }
      *(uint4*)(op + cg * 4) = o;
#pragma unroll
      for (int t = 0; t < 4; t++) {
        float f0 = fin(acc[8 + 2 * t]     + loadF(bb, fB, 64 + cg * 8 + 2 * t));
        float f1 = fin(acc[8 + 2 * t + 1] + loadF(bb, fB, 64 + cg * 8 + 2 * t + 1));
        ou[t] = (unsigned)f2bf(f0) | ((unsigned)f2bf(f1) << 16);
      }
      *(uint4*)(op + 32 + cg * 4) = o;
    } else {
      float* op = xr + (size_t)row * 128;
#pragma unroll
      for (int j = 0; j < 8; j++) op[cg * 8 + j]      = fin(acc[j]     + loadF(bb, fB, cg * 8 + j));
#pragma unroll
      for (int j = 0; j < 8; j++) op[64 + cg * 8 + j] = fin(acc[8 + j] + loadF(bb, fB, 64 + cg * 8 + j));
    }
  }
}

// ---------- layer-2 GEMM: xl2(packed bf16) / xr2(f32) = h@W + b  [N,128]x[128,64] ----------
__global__ __launch_bounds__(256) void k_gemm2(
    const float* __restrict__ h,
    const void* __restrict__ Wl, const void* __restrict__ bl,
    const void* __restrict__ Wr, const void* __restrict__ br,
    const int* __restrict__ flags,
    unsigned int* __restrict__ xlp, float* __restrict__ xr)
{
  __shared__ float hs[32 * 132];
  __shared__ unsigned short ws[128 * 64];
  const void* W  = blockIdx.y ? Wr : Wl;
  const void* bb = blockIdx.y ? br : bl;
  int fW = blockIdx.y ? flags[11] : flags[9];
  int fB = blockIdx.y ? flags[12] : flags[10];
  int tid = threadIdx.x;
  int row0 = blockIdx.x * 32;
  stageW(ws, W, 128 * 64, fW, tid);
  for (int i = tid * 4; i < 32 * 128; i += 1024) {
    int r = i >> 7, k = i & 127;
    int row = row0 + r;
    float4 v = make_float4(0.f, 0.f, 0.f, 0.f);
    if (row < N_NODES) v = *(const float4*)(h + (size_t)row * 128 + k);
    *(float4*)(hs + r * 132 + k) = v;
  }
  __syncthreads();
  int r = tid >> 3, cg = tid & 7;
  float acc[8];
#pragma unroll
  for (int j = 0; j < 8; j++) acc[j] = 0.f;
#pragma unroll 4
  for (int k = 0; k < 128; k++) {
    float hv = hs[r * 132 + k];
    uint4 p = *(const uint4*)(ws + k * 64 + cg * 8);
    acc[0] = fmaf(hv, lo16(p.x), acc[0]); acc[1] = fmaf(hv, hi16(p.x), acc[1]);
    acc[2] = fmaf(hv, lo16(p.y), acc[2]); acc[3] = fmaf(hv, hi16(p.y), acc[3]);
    acc[4] = fmaf(hv, lo16(p.z), acc[4]); acc[5] = fmaf(hv, hi16(p.z), acc[5]);
    acc[6] = fmaf(hv, lo16(p.w), acc[6]); acc[7] = fmaf(hv, hi16(p.w), acc[7]);
  }
  int row = row0 + r;
  if (row < N_NODES) {
    if (blockIdx.y == 0) {        // packed bf16: uint[N][32]
      uint4 o;
      unsigned int* ou = (unsigned int*)&o;
#pragma unroll
      for (int t = 0; t < 4; t++) {
        float f0 = fin(acc[2 * t]     + loadF(bb, fB, cg * 8 + 2 * t));
        float f1 = fin(acc[2 * t + 1] + loadF(bb, fB, cg * 8 + 2 * t + 1));
        ou[t] = (unsigned)f2bf(f0) | ((unsigned)f2bf(f1) << 16);
      }
      *(uint4*)(xlp + (size_t)row * 32 + cg * 4) = o;
    } else {
      float* op = xr + (size_t)row * 64;
#pragma unroll
      for (int j = 0; j < 8; j++) op[cg * 8 + j] = fin(acc[j] + loadF(bb, fB, cg * 8 + j));
    }
  }
}

// ---------- CSR build ----------
__global__ __launch_bounds__(256) void k_hist(const int* __restrict__ ei, int* __restrict__ counts)
{
  int e = blockIdx.x * 256 + threadIdx.x;
  if (e < N_EDGES) {
    int d = ei[N_EDGES + e]; if ((unsigned)d >= N_NODES) d = 0;
    atomicAdd(&counts[d], 1);
  }
}

__global__ __launch_bounds__(256) void k_scan1(const int* __restrict__ counts,
                                               int* __restrict__ row_ptr, int* __restrict__ bsum)
{
  __shared__ int lds[256];
  int t = threadIdx.x;
  int base = blockIdx.x * 1024 + t * 4;
  int c0 = (base + 0) < N_NODES ? counts[base + 0] : 0;
  int c1 = (base + 1) < N_NODES ? counts[base + 1] : 0;
  int c2 = (base + 2) < N_NODES ? counts[base + 2] : 0;
  int c3 = (base + 3) < N_NODES ? counts[base + 3] : 0;
  int s = c0 + c1 + c2 + c3;
  lds[t] = s; __syncthreads();
  for (int off = 1; off < 256; off <<= 1) {
    int v = (t >= off) ? lds[t - off] : 0;
    __syncthreads();
    lds[t] += v;
    __syncthreads();
  }
  int incl = lds[t];
  int excl = incl - s;
  if (base + 0 < N_NODES) row_ptr[base + 0] = excl;
  if (base + 1 < N_NODES) row_ptr[base + 1] = excl + c0;
  if (base + 2 < N_NODES) row_ptr[base + 2] = excl + c0 + c1;
  if (base + 3 < N_NODES) row_ptr[base + 3] = excl + c0 + c1 + c2;
  if (t == 255) bsum[blockIdx.x] = incl;
}

__global__ __launch_bounds__(64) void k_scan2(int* __restrict__ bsum, int nb)
{
  __shared__ int l[64];
  int t = threadIdx.x;
  if (t < nb) l[t] = bsum[t];
  __syncthreads();
  if (t == 0) { int run = 0; for (int i = 0; i < nb; i++) { int v = l[i]; l[i] = run; run += v; } }
  __syncthreads();
  if (t < nb) bsum[t] = l[t];
}

__global__ __launch_bounds__(256) void k_scan3(int* __restrict__ row_ptr, int* __restrict__ cursor,
                                               const int* __restrict__ bsum)
{
  int t = threadIdx.x;
  int base = blockIdx.x * 1024 + t * 4;
  int add = bsum[blockIdx.x];
#pragma unroll
  for (int j = 0; j < 4; j++) {
    int i = base + j;
    if (i < N_NODES) { int v = row_ptr[i] + add; row_ptr[i] = v; cursor[i] = v; }
  }
  if (blockIdx.x == 0 && t == 0) row_ptr[N_NODES] = N_EDGES;
}

__global__ __launch_bounds__(256) void k_scatter(const int* __restrict__ ei,
                                                 int* __restrict__ cursor, int* __restrict__ col)
{
  int e = blockIdx.x * 256 + threadIdx.x;
  if (e < N_EDGES) {
    int d = ei[N_EDGES + e]; if ((unsigned)d >= N_NODES) d = 0;
    int p = atomicAdd(&cursor[d], 1);
    if ((unsigned)p < N_EDGES) col[p] = e;
  }
}

// ---------- fused layer-1: scores + softmax + aggregate + ELU ----------
// wave per node; lane holds channels 2*lane, 2*lane+1; heads = 16-lane groups
__global__ __launch_bounds__(256) void k_fused1(
    const int* __restrict__ ei, const int* __restrict__ row_ptr, const int* __restrict__ col,
    const unsigned int* __restrict__ xlp, const float* __restrict__ xr,
    const unsigned int* __restrict__ ee1u,
    const void* __restrict__ ea, const void* __restrict__ We,
    const void* __restrict__ att, const void* __restrict__ bias,
    const int* __restrict__ flags, int use_ee,
    float* __restrict__ hout)
{
  __shared__ unsigned short wes[32 * 128];   // fallback only
  __shared__ float at[128];
  int tid = threadIdx.x;
  if (!use_ee) stageW(wes, We, 4096, flags[6], tid);
  if (tid < 128) at[tid] = loadF(att, flags[7], tid);
  __syncthreads();
  int i = blockIdx.x * 4 + (tid >> 6);
  int lane = tid & 63;
  float at0 = at[2 * lane], at1 = at[2 * lane + 1];
  float2 xrv = *(const float2*)(xr + (size_t)i * 128 + 2 * lane);
  int p0 = row_ptr[i], p1 = row_ptr[i + 1];
  float acc0 = 0.f, acc1 = 0.f, den = 0.f;
  int fEA = flags[1];
  const unsigned int* wep = (const unsigned int*)wes;
  if (use_ee) {
    int j = p0;
    for (; j + 2 <= p1; j += 2) {
      int e_a = col[j], e_b = col[j + 1];
      int s_a = ei[e_a], s_b = ei[e_b];
      unsigned int uxa = xlp[(size_t)s_a * 64 + lane];
      unsigned int uxb = xlp[(size_t)s_b * 64 + lane];
      unsigned int uea = ee1u[(size_t)e_a * 64 + lane];
      unsigned int ueb = ee1u[(size_t)e_b * 64 + lane];
      float xa0 = lo16(uxa), xa1 = hi16(uxa);
      float xb0 = lo16(uxb), xb1 = hi16(uxb);
      float ma0 = xa0 + xrv.x + lo16(uea);
      float ma1 = xa1 + xrv.y + hi16(uea);
      float mb0 = xb0 + xrv.x + lo16(ueb);
      float mb1 = xb1 + xrv.y + hi16(ueb);
      ma0 = ma0 > 0.f ? ma0 : 0.2f * ma0;
      ma1 = ma1 > 0.f ? ma1 : 0.2f * ma1;
      mb0 = mb0 > 0.f ? mb0 : 0.2f * mb0;
      mb1 = mb1 > 0.f ? mb1 : 0.2f * mb1;
      float pa = fmaf(at0, ma0, at1 * ma1);
      float pb = fmaf(at0, mb0, at1 * mb1);
      pa += __shfl_xor(pa, 1, 64);  pb += __shfl_xor(pb, 1, 64);
      pa += __shfl_xor(pa, 2, 64);  pb += __shfl_xor(pb, 2, 64);
      pa += __shfl_xor(pa, 4, 64);  pb += __shfl_xor(pb, 4, 64);
      pa += __shfl_xor(pa, 8, 64);  pb += __shfl_xor(pb, 8, 64);
      float wa = __expf(fminf(pa, 25.f));
      float wb = __expf(fminf(pb, 25.f));
      acc0 = fmaf(wa, xa0, acc0); acc1 = fmaf(wa, xa1, acc1); den += wa;
      acc0 = fmaf(wb, xb0, acc0); acc1 = fmaf(wb, xb1, acc1); den += wb;
    }
    if (j < p1) {
      int e = col[j];
      int s = ei[e];
      unsigned int ux = xlp[(size_t)s * 64 + lane];
      unsigned int ue = ee1u[(size_t)e * 64 + lane];
      float x0 = lo16(ux), x1 = hi16(ux);
      float m0 = x0 + xrv.x + lo16(ue);
      float m1 = x1 + xrv.y + hi16(ue);
      m0 = m0 > 0.f ? m0 : 0.2f * m0;
      m1 = m1 > 0.f ? m1 : 0.2f * m1;
      float pl = fmaf(at0, m0, at1 * m1);
      pl += __shfl_xor(pl, 1, 64);
      pl += __shfl_xor(pl, 2, 64);
      pl += __shfl_xor(pl, 4, 64);
      pl += __shfl_xor(pl, 8, 64);
      float w = __expf(fminf(pl, 25.f));
      acc0 = fmaf(w, x0, acc0); acc1 = fmaf(w, x1, acc1); den += w;
    }
  } else {
    for (int j = p0; j < p1; j++) {
      int e = col[j];
      int s = ei[e];
      unsigned int ux = xlp[(size_t)s * 64 + lane];
      float x0 = lo16(ux), x1 = hi16(ux);
      float eav = (lane < 32) ? loadF(ea, fEA, (size_t)e * 32 + lane) : 0.f;
      float e0 = 0.f, e1 = 0.f;
#pragma unroll
      for (int k = 0; k < 32; k++) {
        float av = __shfl(eav, k, 64);
        unsigned int p = wep[k * 64 + lane];
        e0 = fmaf(av, lo16(p), e0);
        e1 = fmaf(av, hi16(p), e1);
      }
      float m0 = x0 + xrv.x + e0;
      float m1 = x1 + xrv.y + e1;
      m0 = m0 > 0.f ? m0 : 0.2f * m0;
      m1 = m1 > 0.f ? m1 : 0.2f * m1;
      float pl = fmaf(at0, m0, at1 * m1);
      pl += __shfl_xor(pl, 1, 64);
      pl += __shfl_xor(pl, 2, 64);
      pl += __shfl_xor(pl, 4, 64);
      pl += __shfl_xor(pl, 8, 64);
      float w = __expf(fminf(pl, 25.f));
      acc0 = fmaf(w, x0, acc0); acc1 = fmaf(w, x1, acc1); den += w;
    }
  }
  float inv = 1.f / (den + 1e-16f);
  float o0 = fin(fmaf(acc0, inv, loadF(bias, flags[8], 2 * lane)));
  float o1 = fin(fmaf(acc1, inv, loadF(bias, flags[8], 2 * lane + 1)));
  o0 = o0 > 0.f ? o0 : __expf(o0) - 1.f;
  o1 = o1 > 0.f ? o1 : __expf(o1) - 1.f;
  *(float2*)(hout + (size_t)i * 128 + 2 * lane) = make_float2(o0, o1);
}

// ---------- fused layer-2: H=1, C=64; write final out ----------
__global__ __launch_bounds__(256) void k_fused2(
    const int* __restrict__ ei, const int* __restrict__ row_ptr, const int* __restrict__ col,
    const unsigned int* __restrict__ xlp, const float* __restrict__ xr,
    const unsigned int* __restrict__ ee2u,
    const void* __restrict__ ea, const void* __restrict__ We,
    const void* __restrict__ att, const void* __restrict__ bias,
    const int* __restrict__ flags, int use_ee,
    void* __restrict__ out)
{
  __shared__ unsigned short wes[32 * 64];
  __shared__ float at[64];
  int tid = threadIdx.x;
  if (!use_ee) stageW(wes, We, 2048, flags[13], tid);
  if (tid < 64) at[tid] = loadF(att, flags[14], tid);
  __syncthreads();
  int i = blockIdx.x * 4 + (tid >> 6);
  int lane = tid & 63;
  float atv = at[lane];
  float xrv = xr[(size_t)i * 64 + lane];
  int p0 = row_ptr[i], p1 = row_ptr[i + 1];
  float acc = 0.f, den = 0.f;
  int fEA = flags[1];
  const unsigned short* xlb = (const unsigned short*)xlp;
  const unsigned short* ee2s = (const unsigned short*)ee2u;
  if (use_ee) {
    int j = p0;
    for (; j + 2 <= p1; j += 2) {
      int e_a = col[j], e_b = col[j + 1];
      int s_a = ei[e_a], s_b = ei[e_b];
      float xa = bf2f(xlb[(size_t)s_a * 64 + lane]);
      float xb = bf2f(xlb[(size_t)s_b * 64 + lane]);
      float eea = bf2f(ee2s[(size_t)e_a * 64 + lane]);
      float eeb = bf2f(ee2s[(size_t)e_b * 64 + lane]);
      float ma = xa + xrv + eea;
      float mb = xb + xrv + eeb;
      ma = ma > 0.f ? ma : 0.2f * ma;
      mb = mb > 0.f ? mb : 0.2f * mb;
      float pa = atv * ma, pb = atv * mb;
      pa += __shfl_xor(pa, 1, 64);   pb += __shfl_xor(pb, 1, 64);
      pa += __shfl_xor(pa, 2, 64);   pb += __shfl_xor(pb, 2, 64);
      pa += __shfl_xor(pa, 4, 64);   pb += __shfl_xor(pb, 4, 64);
      pa += __shfl_xor(pa, 8, 64);   pb += __shfl_xor(pb, 8, 64);
      pa += __shfl_xor(pa, 16, 64);  pb += __shfl_xor(pb, 16, 64);
      pa += __shfl_xor(pa, 32, 64);  pb += __shfl_xor(pb, 32, 64);
      float wa = __expf(fminf(pa, 25.f));
      float wb = __expf(fminf(pb, 25.f));
      acc = fmaf(wa, xa, acc); den += wa;
      acc = fmaf(wb, xb, acc); den += wb;
    }
    if (j < p1) {
      int e = col[j];
      int s = ei[e];
      float xv = bf2f(xlb[(size_t)s * 64 + lane]);
      float ee = bf2f(ee2s[(size_t)e * 64 + lane]);
      float m = xv + xrv + ee;
      m = m > 0.f ? m : 0.2f * m;
      float pl = atv * m;
      pl += __shfl_xor(pl, 1, 64);
      pl += __shfl_xor(pl, 2, 64);
      pl += __shfl_xor(pl, 4, 64);
      pl += __shfl_xor(pl, 8, 64);
      pl += __shfl_xor(pl, 16, 64);
      pl += __shfl_xor(pl, 32, 64);
      float w = __expf(fminf(pl, 25.f));
      acc = fmaf(w, xv, acc); den += w;
    }
  } else {
    for (int j = p0; j < p1; j++) {
      int e = col[j];
      int s = ei[e];
      float xv = bf2f(xlb[(size_t)s * 64 + lane]);
      float eav = (lane < 32) ? loadF(ea, fEA, (size_t)e * 32 + lane) : 0.f;
      float ee = 0.f;
#pragma unroll
      for (int k = 0; k < 32; k++) {
        float av = __shfl(eav, k, 64);
        ee = fmaf(av, bf2f(wes[k * 64 + lane]), ee);
      }
      float m = xv + xrv + ee;
      m = m > 0.f ? m : 0.2f * m;
      float pl = atv * m;
      pl += __shfl_xor(pl, 1, 64);
      pl += __shfl_xor(pl, 2, 64);
      pl += __shfl_xor(pl, 4, 64);
      pl += __shfl_xor(pl, 8, 64);
      pl += __shfl_xor(pl, 16, 64);
      pl += __shfl_xor(pl, 32, 64);
      float w = __expf(fminf(pl, 25.f));
      acc = fmaf(w, xv, acc); den += w;
    }
  }
  float inv = 1.f / (den + 1e-16f);
  float o = fin(fmaf(acc, inv, loadF(bias, flags[15], lane)));
  if (flags[0]) ((float*)out)[(size_t)i * 64 + lane] = o;
  else ((unsigned short*)out)[(size_t)i * 64 + lane] = f2bf(o);
}

extern "C" void kernel_launch(void* const* d_in, const int* in_sizes, int n_in,
                              void* d_out, int out_size, void* d_ws, size_t ws_size,
                              hipStream_t stream)
{
  (void)n_in; (void)out_size;
  const void* x    = d_in[0];
  const int*  ei   = (const int*)d_in[1];
  const void* ea   = d_in[2];
  const void* Wl1  = d_in[3];
  const void* bl1  = d_in[4];
  const void* Wr1  = d_in[5];
  const void* br1  = d_in[6];
  const void* We1  = d_in[7];
  const void* att1 = d_in[8];
  const void* bias1= d_in[9];
  const void* Wl2  = d_in[10];
  const void* bl2  = d_in[11];
  const void* Wr2  = d_in[12];
  const void* br2  = d_in[13];
  const void* We2  = d_in[14];
  const void* att2 = d_in[15];
  const void* bias2= d_in[16];

  char* ws = (char*)d_ws;
  size_t off = 0;
  auto take = [&](size_t bytes) -> char* {
    char* p = ws + off;
    off += (bytes + 255) & ~(size_t)255;
    return p;
  };
  unsigned int* xl1p = (unsigned int*)take((size_t)N_NODES * 64 * 4);   // 12.8 MB packed bf16
  float* xr1    = (float*)take((size_t)N_NODES * 128 * 4);              // 25.6 MB
  float* hbuf   = (float*)take((size_t)N_NODES * 128 * 4);              // 25.6 MB
  int*   counts = (int*)  take((size_t)N_NODES * 4);
  int*   row_ptr= (int*)  take((size_t)(N_NODES + 1) * 4);
  int*   cursor = (int*)  take((size_t)N_NODES * 4);
  int*   col    = (int*)  take((size_t)N_EDGES * 4);
  int*   bsum   = (int*)  take(64 * 4);
  int*   flags  = (int*)  take(64 * 4);
  size_t base_end = off;
  unsigned int* ee1u = (unsigned int*)take((size_t)N_EDGES * 64 * 4);  // 204.8 MB
  unsigned int* ee2u = (unsigned int*)take((size_t)N_EDGES * 32 * 4);  // 102.4 MB
  int use_ee = (off <= ws_size) ? 1 : 0;
  if (!use_ee) { ee1u = (unsigned int*)(ws + base_end); ee2u = ee1u; }
  unsigned int* xl2p = xl1p;   // layer-2 reuses (N*32 uints <= N*64 uints)
  float* xr2 = xr1;            // (N*64 floats <= N*128 floats)

  Ptrs tl;
  const int map[16] = {0, 2, 3, 4, 5, 6, 7, 8, 9, 10, 11, 12, 13, 14, 15, 16};
  for (int j = 0; j < 16; j++) { tl.p[j] = d_in[map[j]]; tl.n[j] = in_sizes[map[j]]; }

  int nb = (N_NODES + 1023) / 1024;
  k_detect<<<16, 256, 0, stream>>>(tl, flags);
  k_zero<<<(N_NODES + 255) / 256, 256, 0, stream>>>(counts, N_NODES);
  if (use_ee)
    k_ee_mfma<<<N_EDGES / 64, 256, 0, stream>>>(ea, We1, We2, flags, ee1u, ee2u);
  k_gemm1<<<dim3((N_NODES + 31) / 32, 2), 256, 0, stream>>>(x, Wl1, bl1, Wr1, br1, flags, xl1p, xr1);
  k_hist<<<(N_EDGES + 255) / 256, 256, 0, stream>>>(ei, counts);
  k_scan1<<<nb, 256, 0, stream>>>(counts, row_ptr, bsum);
  k_scan2<<<1, 64, 0, stream>>>(bsum, nb);
  k_scan3<<<nb, 256, 0, stream>>>(row_ptr, cursor, bsum);
  k_scatter<<<(N_EDGES + 255) / 256, 256, 0, stream>>>(ei, cursor, col);
  k_fused1<<<N_NODES / 4, 256, 0, stream>>>(ei, row_ptr, col, xl1p, xr1, ee1u,
                                            ea, We1, att1, bias1, flags, use_ee, hbuf);
  k_gemm2<<<dim3((N_NODES + 31) / 32, 2), 256, 0, stream>>>(hbuf, Wl2, bl2, Wr2, br2, flags, xl2p, xr2);
  k_fused2<<<N_NODES / 4, 256, 0, stream>>>(ei, row_ptr, col, xl2p, xr2, ee2u,
                                            ea, We2, att2, bias2, flags, use_ee, d_out);
}

// Round 5
// 886.524 us; speedup vs baseline: 1.7192x; 1.1249x over previous
//
#include <hip/hip_runtime.h>
#include <stdint.h>

#define N_NODES 50000
#define N_EDGES 800000

// flag indices: 0:x 1:ea 2:Wl1 3:bl1 4:Wr1 5:br1 6:We1 7:att1 8:bias1
//               9:Wl2 10:bl2 11:Wr2 12:br2 13:We2 14:att2 15:bias2
struct Ptrs { const void* p[16]; int n[16]; };

typedef __attribute__((ext_vector_type(8))) short bf16x8;
typedef __attribute__((ext_vector_type(4))) float f32x4;

__device__ __forceinline__ float bf2f(unsigned short u){
  union { unsigned int i; float f; } v; v.i = ((unsigned int)u) << 16; return v.f;
}
__device__ __forceinline__ float lo16(unsigned int u){ union { unsigned int i; float f; } v; v.i = u << 16; return v.f; }
__device__ __forceinline__ float hi16(unsigned int u){ union { unsigned int i; float f; } v; v.i = u & 0xffff0000u; return v.f; }
__device__ __forceinline__ unsigned short f2bf(float f){
  if (!(f == f)) return 0;
  unsigned int x = __float_as_uint(f);
  unsigned int r = (x + 0x7fffu + ((x >> 16) & 1u)) >> 16;
  return (unsigned short)r;
}
__device__ __forceinline__ float fin(float v){
  if (!(v == v)) return 0.f;
  return fminf(fmaxf(v, -1e30f), 1e30f);
}
__device__ __forceinline__ float loadF(const void* p, int f32, size_t idx){
  return f32 ? ((const float*)p)[idx] : bf2f(((const unsigned short*)p)[idx]);
}

// stage n bf16 elems of W (bf16 or f32 source) into LDS; n multiple of 2048
__device__ __forceinline__ void stageW(unsigned short* dst, const void* src, int n, int f32, int tid){
  if (f32) {
    for (int i = tid * 8; i < n; i += 2048) {
      float4 a = *(const float4*)((const float*)src + i);
      float4 b = *(const float4*)((const float*)src + i + 4);
      uint4 u;
      u.x = (unsigned)f2bf(a.x) | ((unsigned)f2bf(a.y) << 16);
      u.y = (unsigned)f2bf(a.z) | ((unsigned)f2bf(a.w) << 16);
      u.z = (unsigned)f2bf(b.x) | ((unsigned)f2bf(b.y) << 16);
      u.w = (unsigned)f2bf(b.z) | ((unsigned)f2bf(b.w) << 16);
      *(uint4*)(dst + i) = u;
    }
  } else {
    for (int i = tid * 8; i < n; i += 2048)
      *(uint4*)(dst + i) = *(const uint4*)((const unsigned short*)src + i);
  }
}

// ---------- dtype detect ----------
__global__ __launch_bounds__(256) void k_detect(Ptrs tl, int* __restrict__ flags)
{
  __shared__ int red[256];
  int b = blockIdx.x, t = threadIdx.x;
  const unsigned short* p = (const unsigned short*)tl.p[b];
  int n = tl.n[b]; if (n > 16384) n = 16384;
  int crazy = 0;
  for (int i = t; i < n; i += 256) {
    unsigned short u = p[i];
    if (u) {
      int ex = (u >> 7) & 0xFF;
      if (ex == 0xFF || ex < 0x60) crazy++;
    }
  }
  red[t] = crazy; __syncthreads();
  for (int off = 128; off; off >>= 1) { if (t < off) red[t] += red[t + off]; __syncthreads(); }
  if (t == 0) flags[b] = (red[0] * 10 > n) ? 1 : 0;
}

__global__ __launch_bounds__(256) void k_zero(int* __restrict__ p, int n)
{
  int i = blockIdx.x * 256 + threadIdx.x;
  if (i < n) p[i] = 0;
}

// ---------- MFMA ee GEMM, CSR-ordered output ----------
// block = 64 edges (4 waves x 16); 12 channel-tiles via mfma_f32_16x16x32_bf16.
// Output row for edge e is written at CSR position pos[e] -> fused kernels stream sequentially.
__global__ __launch_bounds__(256) void k_ee_mfma(
    const void* __restrict__ ea, const void* __restrict__ We1, const void* __restrict__ We2,
    const int* __restrict__ pos, const int* __restrict__ flags,
    unsigned int* __restrict__ ee1u, unsigned int* __restrict__ ee2u)
{
  __shared__ unsigned short wt[192 * 32];     // WeT[ch][k]; ch 0..127 = We1, 128..191 = We2
  __shared__ unsigned short eas[64 * 40];     // ea tile [edge][k], stride 40
  __shared__ unsigned short outs[64 * 200];   // [edge][ch], stride 200
  __shared__ int poss[64];
  int tid = threadIdx.x;
  {
    int f = flags[6];
    for (int i = tid; i < 4096; i += 256) {            // We1[k][c] -> wt[c*32+k]
      int k = i >> 7, c = i & 127;
      wt[c * 32 + k] = f ? f2bf(((const float*)We1)[i]) : ((const unsigned short*)We1)[i];
    }
    f = flags[13];
    for (int i = tid; i < 2048; i += 256) {            // We2[k][c] -> wt[(128+c)*32+k]
      int k = i >> 6, c = i & 63;
      wt[(128 + c) * 32 + k] = f ? f2bf(((const float*)We2)[i]) : ((const unsigned short*)We2)[i];
    }
  }
  size_t e0 = (size_t)blockIdx.x * 64;
  if (tid < 64) poss[tid] = pos[e0 + tid];
  if (flags[1]) {
    for (int i = tid * 4; i < 2048; i += 1024) {
      int r = i >> 5, k = i & 31;
      float4 v = *(const float4*)((const float*)ea + e0 * 32 + i);
      unsigned short* dp = eas + r * 40 + k;
      dp[0] = f2bf(v.x); dp[1] = f2bf(v.y); dp[2] = f2bf(v.z); dp[3] = f2bf(v.w);
    }
  } else {
    for (int i = tid * 4; i < 2048; i += 1024) {
      int r = i >> 5, k = i & 31;
      *(uint2*)(eas + r * 40 + k) = *(const uint2*)((const unsigned short*)ea + e0 * 32 + i);
    }
  }
  __syncthreads();
  int wv = tid >> 6, lane = tid & 63;
  int idx16 = lane & 15, quad = lane >> 4;
  int el = wv * 16;
  bf16x8 bfrag = *(const bf16x8*)(eas + (el + idx16) * 40 + quad * 8);
#pragma unroll
  for (int t = 0; t < 12; t++) {
    bf16x8 afrag = *(const bf16x8*)(wt + (t * 16 + idx16) * 32 + quad * 8);
    f32x4 c = {0.f, 0.f, 0.f, 0.f};
    c = __builtin_amdgcn_mfma_f32_16x16x32_bf16(afrag, bfrag, c, 0, 0, 0);
    unsigned int u0 = (unsigned)f2bf(c[0]) | ((unsigned)f2bf(c[1]) << 16);
    unsigned int u1 = (unsigned)f2bf(c[2]) | ((unsigned)f2bf(c[3]) << 16);
    *(uint2*)(outs + (el + idx16) * 200 + t * 16 + quad * 4) = make_uint2(u0, u1);
  }
#pragma unroll
  for (int r = 0; r < 4; r++) {
    int e = el + (lane >> 4) + r * 4;
    size_t dp = (size_t)poss[e];
    uint4 v = *(const uint4*)(outs + e * 200 + (lane & 15) * 8);
    *(uint4*)(ee1u + dp * 64 + (lane & 15) * 4) = v;
  }
#pragma unroll
  for (int r = 0; r < 2; r++) {
    int e = el + (lane >> 3) + r * 8;
    size_t dp = (size_t)poss[e];
    uint4 v = *(const uint4*)(outs + e * 200 + 128 + (lane & 7) * 8);
    *(uint4*)(ee2u + dp * 32 + (lane & 7) * 4) = v;
  }
}

// ---------- layer-1 GEMM: xl(packed bf16) / xr(f32) = x@W + b ----------
__global__ __launch_bounds__(256) void k_gemm1(
    const void* __restrict__ x,
    const void* __restrict__ Wl, const void* __restrict__ bl,
    const void* __restrict__ Wr, const void* __restrict__ br,
    const int* __restrict__ flags,
    unsigned int* __restrict__ xlp, float* __restrict__ xr)
{
  __shared__ float xs[32 * 132];
  __shared__ unsigned short ws[128 * 128];
  const void* W  = blockIdx.y ? Wr : Wl;
  const void* bb = blockIdx.y ? br : bl;
  int fW = blockIdx.y ? flags[4] : flags[2];
  int fB = blockIdx.y ? flags[5] : flags[3];
  int fX = flags[0];
  int tid = threadIdx.x;
  int row0 = blockIdx.x * 32;
  stageW(ws, W, 128 * 128, fW, tid);
  for (int i = tid * 4; i < 32 * 128; i += 1024) {
    int r = i >> 7, k = i & 127;
    int row = row0 + r;
    float4 v = make_float4(0.f, 0.f, 0.f, 0.f);
    if (row < N_NODES) {
      if (fX) v = *(const float4*)((const float*)x + (size_t)row * 128 + k);
      else {
        uint2 u = *(const uint2*)((const unsigned short*)x + (size_t)row * 128 + k);
        v.x = lo16(u.x); v.y = hi16(u.x); v.z = lo16(u.y); v.w = hi16(u.y);
      }
    }
    *(float4*)(xs + r * 132 + k) = v;
  }
  __syncthreads();
  int r = tid >> 3, cg = tid & 7;
  float acc[16];
#pragma unroll
  for (int j = 0; j < 16; j++) acc[j] = 0.f;
#pragma unroll 4
  for (int k = 0; k < 128; k++) {
    float xv = xs[r * 132 + k];
    uint4 p0 = *(const uint4*)(ws + k * 128 + cg * 8);
    uint4 p1 = *(const uint4*)(ws + k * 128 + 64 + cg * 8);
    acc[0]  = fmaf(xv, lo16(p0.x), acc[0]);  acc[1]  = fmaf(xv, hi16(p0.x), acc[1]);
    acc[2]  = fmaf(xv, lo16(p0.y), acc[2]);  acc[3]  = fmaf(xv, hi16(p0.y), acc[3]);
    acc[4]  = fmaf(xv, lo16(p0.z), acc[4]);  acc[5]  = fmaf(xv, hi16(p0.z), acc[5]);
    acc[6]  = fmaf(xv, lo16(p0.w), acc[6]);  acc[7]  = fmaf(xv, hi16(p0.w), acc[7]);
    acc[8]  = fmaf(xv, lo16(p1.x), acc[8]);  acc[9]  = fmaf(xv, hi16(p1.x), acc[9]);
    acc[10] = fmaf(xv, lo16(p1.y), acc[10]); acc[11] = fmaf(xv, hi16(p1.y), acc[11]);
    acc[12] = fmaf(xv, lo16(p1.z), acc[12]); acc[13] = fmaf(xv, hi16(p1.z), acc[13]);
    acc[14] = fmaf(xv, lo16(p1.w), acc[14]); acc[15] = fmaf(xv, hi16(p1.w), acc[15]);
  }
  int row = row0 + r;
  if (row < N_NODES) {
    if (blockIdx.y == 0) {
      unsigned int* op = xlp + (size_t)row * 64;
      uint4 o;
      unsigned int* ou = (unsigned int*)&o;
#pragma unroll
      for (int t = 0; t < 4; t++) {
        float f0 = fin(acc[2 * t]     + loadF(bb, fB, cg * 8 + 2 * t));
        float f1 = fin(acc[2 * t + 1] + loadF(bb, fB, cg * 8 + 2 * t + 1));
        ou[t] = (unsigned)f2bf(f0) | ((unsigned)f2bf(f1) << 16);
      }
      *(uint4*)(op + cg * 4) = o;
#pragma unroll
      for (int t = 0; t < 4; t++) {
        float f0 = fin(acc[8 + 2 * t]     + loadF(bb, fB, 64 + cg * 8 + 2 * t));
        float f1 = fin(acc[8 + 2 * t + 1] + loadF(bb, fB, 64 + cg * 8 + 2 * t + 1));
        ou[t] = (unsigned)f2bf(f0) | ((unsigned)f2bf(f1) << 16);
      }
      *(uint4*)(op + 32 + cg * 4) = o;
    } else {
      float* op = xr + (size_t)row * 128;
#pragma unroll
      for (int j = 0; j < 8; j++) op[cg * 8 + j]      = fin(acc[j]     + loadF(bb, fB, cg * 8 + j));
#pragma unroll
      for (int j = 0; j < 8; j++) op[64 + cg * 8 + j] = fin(acc[8 + j] + loadF(bb, fB, 64 + cg * 8 + j));
    }
  }
}

// ---------- layer-2 GEMM: xl2(packed bf16) / xr2(f32) = h@W + b ----------
__global__ __launch_bounds__(256) void k_gemm2(
    const float* __restrict__ h,
    const void* __restrict__ Wl, const void* __restrict__ bl,
    const void* __restrict__ Wr, const void* __restrict__ br,
    const int* __restrict__ flags,
    unsigned int* __restrict__ xlp, float* __restrict__ xr)
{
  __shared__ float hs[32 * 132];
  __shared__ unsigned short ws[128 * 64];
  const void* W  = blockIdx.y ? Wr : Wl;
  const void* bb = blockIdx.y ? br : bl;
  int fW = blockIdx.y ? flags[11] : flags[9];
  int fB = blockIdx.y ? flags[12] : flags[10];
  int tid = threadIdx.x;
  int row0 = blockIdx.x * 32;
  stageW(ws, W, 128 * 64, fW, tid);
  for (int i = tid * 4; i < 32 * 128; i += 1024) {
    int r = i >> 7, k = i & 127;
    int row = row0 + r;
    float4 v = make_float4(0.f, 0.f, 0.f, 0.f);
    if (row < N_NODES) v = *(const float4*)(h + (size_t)row * 128 + k);
    *(float4*)(hs + r * 132 + k) = v;
  }
  __syncthreads();
  int r = tid >> 3, cg = tid & 7;
  float acc[8];
#pragma unroll
  for (int j = 0; j < 8; j++) acc[j] = 0.f;
#pragma unroll 4
  for (int k = 0; k < 128; k++) {
    float hv = hs[r * 132 + k];
    uint4 p = *(const uint4*)(ws + k * 64 + cg * 8);
    acc[0] = fmaf(hv, lo16(p.x), acc[0]); acc[1] = fmaf(hv, hi16(p.x), acc[1]);
    acc[2] = fmaf(hv, lo16(p.y), acc[2]); acc[3] = fmaf(hv, hi16(p.y), acc[3]);
    acc[4] = fmaf(hv, lo16(p.z), acc[4]); acc[5] = fmaf(hv, hi16(p.z), acc[5]);
    acc[6] = fmaf(hv, lo16(p.w), acc[6]); acc[7] = fmaf(hv, hi16(p.w), acc[7]);
  }
  int row = row0 + r;
  if (row < N_NODES) {
    if (blockIdx.y == 0) {
      uint4 o;
      unsigned int* ou = (unsigned int*)&o;
#pragma unroll
      for (int t = 0; t < 4; t++) {
        float f0 = fin(acc[2 * t]     + loadF(bb, fB, cg * 8 + 2 * t));
        float f1 = fin(acc[2 * t + 1] + loadF(bb, fB, cg * 8 + 2 * t + 1));
        ou[t] = (unsigned)f2bf(f0) | ((unsigned)f2bf(f1) << 16);
      }
      *(uint4*)(xlp + (size_t)row * 32 + cg * 4) = o;
    } else {
      float* op = xr + (size_t)row * 64;
#pragma unroll
      for (int j = 0; j < 8; j++) op[cg * 8 + j] = fin(acc[j] + loadF(bb, fB, cg * 8 + j));
    }
  }
}

// ---------- CSR build ----------
__global__ __launch_bounds__(256) void k_hist(const int* __restrict__ ei, int* __restrict__ counts)
{
  int e = blockIdx.x * 256 + threadIdx.x;
  if (e < N_EDGES) {
    int d = ei[N_EDGES + e]; if ((unsigned)d >= N_NODES) d = 0;
    atomicAdd(&counts[d], 1);
  }
}

__global__ __launch_bounds__(256) void k_scan1(const int* __restrict__ counts,
                                               int* __restrict__ row_ptr, int* __restrict__ bsum)
{
  __shared__ int lds[256];
  int t = threadIdx.x;
  int base = blockIdx.x * 1024 + t * 4;
  int c0 = (base + 0) < N_NODES ? counts[base + 0] : 0;
  int c1 = (base + 1) < N_NODES ? counts[base + 1] : 0;
  int c2 = (base + 2) < N_NODES ? counts[base + 2] : 0;
  int c3 = (base + 3) < N_NODES ? counts[base + 3] : 0;
  int s = c0 + c1 + c2 + c3;
  lds[t] = s; __syncthreads();
  for (int off = 1; off < 256; off <<= 1) {
    int v = (t >= off) ? lds[t - off] : 0;
    __syncthreads();
    lds[t] += v;
    __syncthreads();
  }
  int incl = lds[t];
  int excl = incl - s;
  if (base + 0 < N_NODES) row_ptr[base + 0] = excl;
  if (base + 1 < N_NODES) row_ptr[base + 1] = excl + c0;
  if (base + 2 < N_NODES) row_ptr[base + 2] = excl + c0 + c1;
  if (base + 3 < N_NODES) row_ptr[base + 3] = excl + c0 + c1 + c2;
  if (t == 255) bsum[blockIdx.x] = incl;
}

__global__ __launch_bounds__(64) void k_scan2(int* __restrict__ bsum, int nb)
{
  __shared__ int l[64];
  int t = threadIdx.x;
  if (t < nb) l[t] = bsum[t];
  __syncthreads();
  if (t == 0) { int run = 0; for (int i = 0; i < nb; i++) { int v = l[i]; l[i] = run; run += v; } }
  __syncthreads();
  if (t < nb) bsum[t] = l[t];
}

__global__ __launch_bounds__(256) void k_scan3(int* __restrict__ row_ptr, int* __restrict__ cursor,
                                               const int* __restrict__ bsum)
{
  int t = threadIdx.x;
  int base = blockIdx.x * 1024 + t * 4;
  int add = bsum[blockIdx.x];
#pragma unroll
  for (int j = 0; j < 4; j++) {
    int i = base + j;
    if (i < N_NODES) { int v = row_ptr[i] + add; row_ptr[i] = v; cursor[i] = v; }
  }
  if (blockIdx.x == 0 && t == 0) row_ptr[N_NODES] = N_EDGES;
}

// writes col (edge id per CSR slot), pos (CSR slot per edge), srcs (src node per CSR slot)
__global__ __launch_bounds__(256) void k_scatter(const int* __restrict__ ei,
                                                 int* __restrict__ cursor, int* __restrict__ col,
                                                 int* __restrict__ pos, int* __restrict__ srcs)
{
  int e = blockIdx.x * 256 + threadIdx.x;
  if (e < N_EDGES) {
    int d = ei[N_EDGES + e]; if ((unsigned)d >= N_NODES) d = 0;
    int s = ei[e];           if ((unsigned)s >= N_NODES) s = 0;
    int p = atomicAdd(&cursor[d], 1);
    if ((unsigned)p < N_EDGES) { col[p] = e; pos[e] = p; srcs[p] = s; }
  }
}

// ---------- fused layer-1: scores + softmax + aggregate + ELU ----------
// wave per node; ee1u is CSR-ordered: row j <-> CSR slot j (sequential stream)
__global__ __launch_bounds__(256) void k_fused1(
    const int* __restrict__ srcs, const int* __restrict__ row_ptr, const int* __restrict__ col,
    const unsigned int* __restrict__ xlp, const float* __restrict__ xr,
    const unsigned int* __restrict__ ee1u,
    const void* __restrict__ ea, const void* __restrict__ We,
    const void* __restrict__ att, const void* __restrict__ bias,
    const int* __restrict__ flags, int use_ee,
    float* __restrict__ hout)
{
  __shared__ unsigned short wes[32 * 128];   // fallback only
  __shared__ float at[128];
  int tid = threadIdx.x;
  if (!use_ee) stageW(wes, We, 4096, flags[6], tid);
  if (tid < 128) at[tid] = loadF(att, flags[7], tid);
  __syncthreads();
  int i = blockIdx.x * 4 + (tid >> 6);
  int lane = tid & 63;
  float at0 = at[2 * lane], at1 = at[2 * lane + 1];
  float2 xrv = *(const float2*)(xr + (size_t)i * 128 + 2 * lane);
  int p0 = row_ptr[i], p1 = row_ptr[i + 1];
  float acc0 = 0.f, acc1 = 0.f, den = 0.f;
  int fEA = flags[1];
  const unsigned int* wep = (const unsigned int*)wes;
  if (use_ee) {
    int j = p0;
    for (; j + 4 <= p1; j += 4) {
      int s0 = srcs[j], s1 = srcs[j + 1], s2 = srcs[j + 2], s3 = srcs[j + 3];
      unsigned int ue0 = ee1u[(size_t)(j + 0) * 64 + lane];
      unsigned int ue1 = ee1u[(size_t)(j + 1) * 64 + lane];
      unsigned int ue2 = ee1u[(size_t)(j + 2) * 64 + lane];
      unsigned int ue3 = ee1u[(size_t)(j + 3) * 64 + lane];
      unsigned int ux0 = xlp[(size_t)s0 * 64 + lane];
      unsigned int ux1 = xlp[(size_t)s1 * 64 + lane];
      unsigned int ux2 = xlp[(size_t)s2 * 64 + lane];
      unsigned int ux3 = xlp[(size_t)s3 * 64 + lane];
#pragma unroll
      for (int q = 0; q < 4; q++) {
        unsigned int ux = q == 0 ? ux0 : q == 1 ? ux1 : q == 2 ? ux2 : ux3;
        unsigned int ue = q == 0 ? ue0 : q == 1 ? ue1 : q == 2 ? ue2 : ue3;
        float x0 = lo16(ux), x1 = hi16(ux);
        float m0 = x0 + xrv.x + lo16(ue);
        float m1 = x1 + xrv.y + hi16(ue);
        m0 = m0 > 0.f ? m0 : 0.2f * m0;
        m1 = m1 > 0.f ? m1 : 0.2f * m1;
        float pl = fmaf(at0, m0, at1 * m1);
        pl += __shfl_xor(pl, 1, 64);
        pl += __shfl_xor(pl, 2, 64);
        pl += __shfl_xor(pl, 4, 64);
        pl += __shfl_xor(pl, 8, 64);
        float w = __expf(fminf(pl, 25.f));
        acc0 = fmaf(w, x0, acc0); acc1 = fmaf(w, x1, acc1); den += w;
      }
    }
    for (; j < p1; j++) {
      int s = srcs[j];
      unsigned int ue = ee1u[(size_t)j * 64 + lane];
      unsigned int ux = xlp[(size_t)s * 64 + lane];
      float x0 = lo16(ux), x1 = hi16(ux);
      float m0 = x0 + xrv.x + lo16(ue);
      float m1 = x1 + xrv.y + hi16(ue);
      m0 = m0 > 0.f ? m0 : 0.2f * m0;
      m1 = m1 > 0.f ? m1 : 0.2f * m1;
      float pl = fmaf(at0, m0, at1 * m1);
      pl += __shfl_xor(pl, 1, 64);
      pl += __shfl_xor(pl, 2, 64);
      pl += __shfl_xor(pl, 4, 64);
      pl += __shfl_xor(pl, 8, 64);
      float w = __expf(fminf(pl, 25.f));
      acc0 = fmaf(w, x0, acc0); acc1 = fmaf(w, x1, acc1); den += w;
    }
  } else {
    for (int j = p0; j < p1; j++) {
      int e = col[j];
      int s = srcs[j];
      unsigned int ux = xlp[(size_t)s * 64 + lane];
      float x0 = lo16(ux), x1 = hi16(ux);
      float eav = (lane < 32) ? loadF(ea, fEA, (size_t)e * 32 + lane) : 0.f;
      float e0 = 0.f, e1 = 0.f;
#pragma unroll
      for (int k = 0; k < 32; k++) {
        float av = __shfl(eav, k, 64);
        unsigned int p = wep[k * 64 + lane];
        e0 = fmaf(av, lo16(p), e0);
        e1 = fmaf(av, hi16(p), e1);
      }
      float m0 = x0 + xrv.x + e0;
      float m1 = x1 + xrv.y + e1;
      m0 = m0 > 0.f ? m0 : 0.2f * m0;
      m1 = m1 > 0.f ? m1 : 0.2f * m1;
      float pl = fmaf(at0, m0, at1 * m1);
      pl += __shfl_xor(pl, 1, 64);
      pl += __shfl_xor(pl, 2, 64);
      pl += __shfl_xor(pl, 4, 64);
      pl += __shfl_xor(pl, 8, 64);
      float w = __expf(fminf(pl, 25.f));
      acc0 = fmaf(w, x0, acc0); acc1 = fmaf(w, x1, acc1); den += w;
    }
  }
  float inv = 1.f / (den + 1e-16f);
  float o0 = fin(fmaf(acc0, inv, loadF(bias, flags[8], 2 * lane)));
  float o1 = fin(fmaf(acc1, inv, loadF(bias, flags[8], 2 * lane + 1)));
  o0 = o0 > 0.f ? o0 : __expf(o0) - 1.f;
  o1 = o1 > 0.f ? o1 : __expf(o1) - 1.f;
  *(float2*)(hout + (size_t)i * 128 + 2 * lane) = make_float2(o0, o1);
}

// ---------- fused layer-2: H=1, C=64; write final out ----------
__global__ __launch_bounds__(256) void k_fused2(
    const int* __restrict__ srcs, const int* __restrict__ row_ptr, const int* __restrict__ col,
    const unsigned int* __restrict__ xlp, const float* __restrict__ xr,
    const unsigned int* __restrict__ ee2u,
    const void* __restrict__ ea, const void* __restrict__ We,
    const void* __restrict__ att, const void* __restrict__ bias,
    const int* __restrict__ flags, int use_ee,
    void* __restrict__ out)
{
  __shared__ unsigned short wes[32 * 64];
  __shared__ float at[64];
  int tid = threadIdx.x;
  if (!use_ee) stageW(wes, We, 2048, flags[13], tid);
  if (tid < 64) at[tid] = loadF(att, flags[14], tid);
  __syncthreads();
  int i = blockIdx.x * 4 + (tid >> 6);
  int lane = tid & 63;
  float atv = at[lane];
  float xrv = xr[(size_t)i * 64 + lane];
  int p0 = row_ptr[i], p1 = row_ptr[i + 1];
  float acc = 0.f, den = 0.f;
  int fEA = flags[1];
  const unsigned short* xlb = (const unsigned short*)xlp;
  const unsigned short* ee2s = (const unsigned short*)ee2u;
  if (use_ee) {
    int j = p0;
    for (; j + 4 <= p1; j += 4) {
      int s0 = srcs[j], s1 = srcs[j + 1], s2 = srcs[j + 2], s3 = srcs[j + 3];
      unsigned short e0s = ee2s[(size_t)(j + 0) * 64 + lane];
      unsigned short e1s = ee2s[(size_t)(j + 1) * 64 + lane];
      unsigned short e2s = ee2s[(size_t)(j + 2) * 64 + lane];
      unsigned short e3s = ee2s[(size_t)(j + 3) * 64 + lane];
      unsigned short x0s = xlb[(size_t)s0 * 64 + lane];
      unsigned short x1s = xlb[(size_t)s1 * 64 + lane];
      unsigned short x2s = xlb[(size_t)s2 * 64 + lane];
      unsigned short x3s = xlb[(size_t)s3 * 64 + lane];
#pragma unroll
      for (int q = 0; q < 4; q++) {
        float xv = bf2f(q == 0 ? x0s : q == 1 ? x1s : q == 2 ? x2s : x3s);
        float ee = bf2f(q == 0 ? e0s : q == 1 ? e1s : q == 2 ? e2s : e3s);
        float m = xv + xrv + ee;
        m = m > 0.f ? m : 0.2f * m;
        float pl = atv * m;
        pl += __shfl_xor(pl, 1, 64);
        pl += __shfl_xor(pl, 2, 64);
        pl += __shfl_xor(pl, 4, 64);
        pl += __shfl_xor(pl, 8, 64);
        pl += __shfl_xor(pl, 16, 64);
        pl += __shfl_xor(pl, 32, 64);
        float w = __expf(fminf(pl, 25.f));
        acc = fmaf(w, xv, acc); den += w;
      }
    }
    for (; j < p1; j++) {
      int s = srcs[j];
      float xv = bf2f(xlb[(size_t)s * 64 + lane]);
      float ee = bf2f(ee2s[(size_t)j * 64 + lane]);
      float m = xv + xrv + ee;
      m = m > 0.f ? m : 0.2f * m;
      float pl = atv * m;
      pl += __shfl_xor(pl, 1, 64);
      pl += __shfl_xor(pl, 2, 64);
      pl += __shfl_xor(pl, 4, 64);
      pl += __shfl_xor(pl, 8, 64);
      pl += __shfl_xor(pl, 16, 64);
      pl += __shfl_xor(pl, 32, 64);
      float w = __expf(fminf(pl, 25.f));
      acc = fmaf(w, xv, acc); den += w;
    }
  } else {
    for (int j = p0; j < p1; j++) {
      int e = col[j];
      int s = srcs[j];
      float xv = bf2f(xlb[(size_t)s * 64 + lane]);
      float eav = (lane < 32) ? loadF(ea, fEA, (size_t)e * 32 + lane) : 0.f;
      float ee = 0.f;
#pragma unroll
      for (int k = 0; k < 32; k++) {
        float av = __shfl(eav, k, 64);
        ee = fmaf(av, bf2f(wes[k * 64 + lane]), ee);
      }
      float m = xv + xrv + ee;
      m = m > 0.f ? m : 0.2f * m;
      float pl = atv * m;
      pl += __shfl_xor(pl, 1, 64);
      pl += __shfl_xor(pl, 2, 64);
      pl += __shfl_xor(pl, 4, 64);
      pl += __shfl_xor(pl, 8, 64);
      pl += __shfl_xor(pl, 16, 64);
      pl += __shfl_xor(pl, 32, 64);
      float w = __expf(fminf(pl, 25.f));
      acc = fmaf(w, xv, acc); den += w;
    }
  }
  float inv = 1.f / (den + 1e-16f);
  float o = fin(fmaf(acc, inv, loadF(bias, flags[15], lane)));
  if (flags[0]) ((float*)out)[(size_t)i * 64 + lane] = o;
  else ((unsigned short*)out)[(size_t)i * 64 + lane] = f2bf(o);
}

extern "C" void kernel_launch(void* const* d_in, const int* in_sizes, int n_in,
                              void* d_out, int out_size, void* d_ws, size_t ws_size,
                              hipStream_t stream)
{
  (void)n_in; (void)out_size;
  const void* x    = d_in[0];
  const int*  ei   = (const int*)d_in[1];
  const void* ea   = d_in[2];
  const void* Wl1  = d_in[3];
  const void* bl1  = d_in[4];
  const void* Wr1  = d_in[5];
  const void* br1  = d_in[6];
  const void* We1  = d_in[7];
  const void* att1 = d_in[8];
  const void* bias1= d_in[9];
  const void* Wl2  = d_in[10];
  const void* bl2  = d_in[11];
  const void* Wr2  = d_in[12];
  const void* br2  = d_in[13];
  const void* We2  = d_in[14];
  const void* att2 = d_in[15];
  const void* bias2= d_in[16];

  char* ws = (char*)d_ws;
  size_t off = 0;
  auto take = [&](size_t bytes) -> char* {
    char* p = ws + off;
    off += (bytes + 255) & ~(size_t)255;
    return p;
  };
  unsigned int* xl1p = (unsigned int*)take((size_t)N_NODES * 64 * 4);   // 12.8 MB
  float* xr1    = (float*)take((size_t)N_NODES * 128 * 4);              // 25.6 MB
  float* hbuf   = (float*)take((size_t)N_NODES * 128 * 4);              // 25.6 MB
  int*   counts = (int*)  take((size_t)N_NODES * 4);
  int*   row_ptr= (int*)  take((size_t)(N_NODES + 1) * 4);
  int*   cursor = (int*)  take((size_t)N_NODES * 4);
  int*   col    = (int*)  take((size_t)N_EDGES * 4);
  int*   pos    = (int*)  take((size_t)N_EDGES * 4);
  int*   srcs   = (int*)  take((size_t)N_EDGES * 4);
  int*   bsum   = (int*)  take(64 * 4);
  int*   flags  = (int*)  take(64 * 4);
  size_t base_end = off;
  unsigned int* ee1u = (unsigned int*)take((size_t)N_EDGES * 64 * 4);  // 204.8 MB
  unsigned int* ee2u = (unsigned int*)take((size_t)N_EDGES * 32 * 4);  // 102.4 MB
  int use_ee = (off <= ws_size) ? 1 : 0;
  if (!use_ee) { ee1u = (unsigned int*)(ws + base_end); ee2u = ee1u; }
  unsigned int* xl2p = xl1p;
  float* xr2 = xr1;

  Ptrs tl;
  const int map[16] = {0, 2, 3, 4, 5, 6, 7, 8, 9, 10, 11, 12, 13, 14, 15, 16};
  for (int j = 0; j < 16; j++) { tl.p[j] = d_in[map[j]]; tl.n[j] = in_sizes[map[j]]; }

  int nb = (N_NODES + 1023) / 1024;
  k_detect<<<16, 256, 0, stream>>>(tl, flags);
  k_zero<<<(N_NODES + 255) / 256, 256, 0, stream>>>(counts, N_NODES);
  k_gemm1<<<dim3((N_NODES + 31) / 32, 2), 256, 0, stream>>>(x, Wl1, bl1, Wr1, br1, flags, xl1p, xr1);
  k_hist<<<(N_EDGES + 255) / 256, 256, 0, stream>>>(ei, counts);
  k_scan1<<<nb, 256, 0, stream>>>(counts, row_ptr, bsum);
  k_scan2<<<1, 64, 0, stream>>>(bsum, nb);
  k_scan3<<<nb, 256, 0, stream>>>(row_ptr, cursor, bsum);
  k_scatter<<<(N_EDGES + 255) / 256, 256, 0, stream>>>(ei, cursor, col, pos, srcs);
  if (use_ee)
    k_ee_mfma<<<N_EDGES / 64, 256, 0, stream>>>(ea, We1, We2, pos, flags, ee1u, ee2u);
  k_fused1<<<N_NODES / 4, 256, 0, stream>>>(srcs, row_ptr, col, xl1p, xr1, ee1u,
                                            ea, We1, att1, bias1, flags, use_ee, hbuf);
  k_gemm2<<<dim3((N_NODES + 31) / 32, 2), 256, 0, stream>>>(hbuf, Wl2, bl2, Wr2, br2, flags, xl2p, xr2);
  k_fused2<<<N_NODES / 4, 256, 0, stream>>>(srcs, row_ptr, col, xl2p, xr2, ee2u,
                                            ea, We2, att2, bias2, flags, use_ee, d_out);
}

// Round 6
// 855.024 us; speedup vs baseline: 1.7826x; 1.0368x over previous
//
#include <hip/hip_runtime.h>
#include <stdint.h>

#define N_NODES 50000
#define N_EDGES 800000

// flag indices: 0:x 1:ea 2:Wl1 3:bl1 4:Wr1 5:br1 6:We1 7:att1 8:bias1
//               9:Wl2 10:bl2 11:Wr2 12:br2 13:We2 14:att2 15:bias2
struct Ptrs { const void* p[16]; int n[16]; };

typedef __attribute__((ext_vector_type(8))) short bf16x8;
typedef __attribute__((ext_vector_type(4))) float f32x4;

__device__ __forceinline__ float bf2f(unsigned short u){
  union { unsigned int i; float f; } v; v.i = ((unsigned int)u) << 16; return v.f;
}
__device__ __forceinline__ float lo16(unsigned int u){ union { unsigned int i; float f; } v; v.i = u << 16; return v.f; }
__device__ __forceinline__ float hi16(unsigned int u){ union { unsigned int i; float f; } v; v.i = u & 0xffff0000u; return v.f; }
__device__ __forceinline__ unsigned short f2bf(float f){
  if (!(f == f)) return 0;
  unsigned int x = __float_as_uint(f);
  unsigned int r = (x + 0x7fffu + ((x >> 16) & 1u)) >> 16;
  return (unsigned short)r;
}
__device__ __forceinline__ float fin(float v){
  if (!(v == v)) return 0.f;
  return fminf(fmaxf(v, -1e30f), 1e30f);
}
__device__ __forceinline__ float loadF(const void* p, int f32, size_t idx){
  return f32 ? ((const float*)p)[idx] : bf2f(((const unsigned short*)p)[idx]);
}

// stage n bf16 elems of W (bf16 or f32 source) into LDS; n multiple of 2048
__device__ __forceinline__ void stageW(unsigned short* dst, const void* src, int n, int f32, int tid){
  if (f32) {
    for (int i = tid * 8; i < n; i += 2048) {
      float4 a = *(const float4*)((const float*)src + i);
      float4 b = *(const float4*)((const float*)src + i + 4);
      uint4 u;
      u.x = (unsigned)f2bf(a.x) | ((unsigned)f2bf(a.y) << 16);
      u.y = (unsigned)f2bf(a.z) | ((unsigned)f2bf(a.w) << 16);
      u.z = (unsigned)f2bf(b.x) | ((unsigned)f2bf(b.y) << 16);
      u.w = (unsigned)f2bf(b.z) | ((unsigned)f2bf(b.w) << 16);
      *(uint4*)(dst + i) = u;
    }
  } else {
    for (int i = tid * 8; i < n; i += 2048)
      *(uint4*)(dst + i) = *(const uint4*)((const unsigned short*)src + i);
  }
}

// ---------- dtype detect ----------
__global__ __launch_bounds__(256) void k_detect(Ptrs tl, int* __restrict__ flags)
{
  __shared__ int red[256];
  int b = blockIdx.x, t = threadIdx.x;
  const unsigned short* p = (const unsigned short*)tl.p[b];
  int n = tl.n[b]; if (n > 16384) n = 16384;
  int crazy = 0;
  for (int i = t; i < n; i += 256) {
    unsigned short u = p[i];
    if (u) {
      int ex = (u >> 7) & 0xFF;
      if (ex == 0xFF || ex < 0x60) crazy++;
    }
  }
  red[t] = crazy; __syncthreads();
  for (int off = 128; off; off >>= 1) { if (t < off) red[t] += red[t + off]; __syncthreads(); }
  if (t == 0) flags[b] = (red[0] * 10 > n) ? 1 : 0;
}

__global__ __launch_bounds__(256) void k_zero(int* __restrict__ p, int n)
{
  int i = blockIdx.x * 256 + threadIdx.x;
  if (i < n) p[i] = 0;
}

// ---------- MFMA ee GEMM, CSR-ordered DIRECT scatter stores ----------
// block = 128 edges (4 waves x 2 tiles of 16). 12 channel-tiles via mfma_f32_16x16x32_bf16.
// Lane (idx16=edge, quad) holds D[ch=16t+4q+r][edge]; uint2 store = 8 B at
// ee[pos[e]*row + ch/2] -> 32 B contiguous per edge per tile, L2 merges to 256 B rows.
// wt stride 34 ushorts (17 dwords, odd) -> conflict-free ds_read_b128.
__global__ __launch_bounds__(256) void k_ee_mfma(
    const void* __restrict__ ea, const void* __restrict__ We1, const void* __restrict__ We2,
    const int* __restrict__ pos, const int* __restrict__ flags,
    unsigned int* __restrict__ ee1u, unsigned int* __restrict__ ee2u)
{
  __shared__ unsigned short wt[192 * 34];   // WeT[ch][k]; ch 0..127 = We1, 128..191 = We2
  int tid = threadIdx.x;
  {
    int f = flags[6];
    for (int i = tid; i < 4096; i += 256) {            // We1[k][c] -> wt[c*34+k]
      int k = i >> 7, c = i & 127;
      wt[c * 34 + k] = f ? f2bf(((const float*)We1)[i]) : ((const unsigned short*)We1)[i];
    }
    f = flags[13];
    for (int i = tid; i < 2048; i += 256) {            // We2[k][c] -> wt[(128+c)*34+k]
      int k = i >> 6, c = i & 63;
      wt[(128 + c) * 34 + k] = f ? f2bf(((const float*)We2)[i]) : ((const unsigned short*)We2)[i];
    }
  }
  __syncthreads();
  int wv = tid >> 6, lane = tid & 63;
  int idx16 = lane & 15, quad = lane >> 4;
  size_t e0 = (size_t)blockIdx.x * 128;
  int fEA = flags[1];
  // hoist the 12 A-fragments (block-invariant)
  bf16x8 af[12];
#pragma unroll
  for (int t = 0; t < 12; t++)
    af[t] = *(const bf16x8*)(wt + (t * 16 + idx16) * 34 + quad * 8);
#pragma unroll
  for (int tt = 0; tt < 2; tt++) {
    size_t erow = e0 + (size_t)wv * 32 + tt * 16 + idx16;
    bf16x8 bfrag;
    if (fEA) {
      const float* p = (const float*)ea + erow * 32 + quad * 8;
      float4 v0 = *(const float4*)p;
      float4 v1 = *(const float4*)(p + 4);
      unsigned short tmp[8] = { f2bf(v0.x), f2bf(v0.y), f2bf(v0.z), f2bf(v0.w),
                                f2bf(v1.x), f2bf(v1.y), f2bf(v1.z), f2bf(v1.w) };
      bfrag = *(const bf16x8*)tmp;
    } else {
      bfrag = *(const bf16x8*)((const unsigned short*)ea + erow * 32 + quad * 8);
    }
    size_t dp = (size_t)pos[erow];
#pragma unroll
    for (int t = 0; t < 12; t++) {
      f32x4 c = {0.f, 0.f, 0.f, 0.f};
      c = __builtin_amdgcn_mfma_f32_16x16x32_bf16(af[t], bfrag, c, 0, 0, 0);
      unsigned int u0 = (unsigned)f2bf(c[0]) | ((unsigned)f2bf(c[1]) << 16);
      unsigned int u1 = (unsigned)f2bf(c[2]) | ((unsigned)f2bf(c[3]) << 16);
      if (t < 8)
        *(uint2*)(ee1u + dp * 64 + t * 8 + quad * 2) = make_uint2(u0, u1);
      else
        *(uint2*)(ee2u + dp * 32 + (t - 8) * 8 + quad * 2) = make_uint2(u0, u1);
    }
  }
}

// ---------- layer-1 GEMM: xl(packed bf16) / xr(f32) = x@W + b ----------
__global__ __launch_bounds__(256) void k_gemm1(
    const void* __restrict__ x,
    const void* __restrict__ Wl, const void* __restrict__ bl,
    const void* __restrict__ Wr, const void* __restrict__ br,
    const int* __restrict__ flags,
    unsigned int* __restrict__ xlp, float* __restrict__ xr)
{
  __shared__ float xs[32 * 132];
  __shared__ unsigned short ws[128 * 128];
  const void* W  = blockIdx.y ? Wr : Wl;
  const void* bb = blockIdx.y ? br : bl;
  int fW = blockIdx.y ? flags[4] : flags[2];
  int fB = blockIdx.y ? flags[5] : flags[3];
  int fX = flags[0];
  int tid = threadIdx.x;
  int row0 = blockIdx.x * 32;
  stageW(ws, W, 128 * 128, fW, tid);
  for (int i = tid * 4; i < 32 * 128; i += 1024) {
    int r = i >> 7, k = i & 127;
    int row = row0 + r;
    float4 v = make_float4(0.f, 0.f, 0.f, 0.f);
    if (row < N_NODES) {
      if (fX) v = *(const float4*)((const float*)x + (size_t)row * 128 + k);
      else {
        uint2 u = *(const uint2*)((const unsigned short*)x + (size_t)row * 128 + k);
        v.x = lo16(u.x); v.y = hi16(u.x); v.z = lo16(u.y); v.w = hi16(u.y);
      }
    }
    *(float4*)(xs + r * 132 + k) = v;
  }
  __syncthreads();
  int r = tid >> 3, cg = tid & 7;
  float acc[16];
#pragma unroll
  for (int j = 0; j < 16; j++) acc[j] = 0.f;
#pragma unroll 4
  for (int k = 0; k < 128; k++) {
    float xv = xs[r * 132 + k];
    uint4 p0 = *(const uint4*)(ws + k * 128 + cg * 8);
    uint4 p1 = *(const uint4*)(ws + k * 128 + 64 + cg * 8);
    acc[0]  = fmaf(xv, lo16(p0.x), acc[0]);  acc[1]  = fmaf(xv, hi16(p0.x), acc[1]);
    acc[2]  = fmaf(xv, lo16(p0.y), acc[2]);  acc[3]  = fmaf(xv, hi16(p0.y), acc[3]);
    acc[4]  = fmaf(xv, lo16(p0.z), acc[4]);  acc[5]  = fmaf(xv, hi16(p0.z), acc[5]);
    acc[6]  = fmaf(xv, lo16(p0.w), acc[6]);  acc[7]  = fmaf(xv, hi16(p0.w), acc[7]);
    acc[8]  = fmaf(xv, lo16(p1.x), acc[8]);  acc[9]  = fmaf(xv, hi16(p1.x), acc[9]);
    acc[10] = fmaf(xv, lo16(p1.y), acc[10]); acc[11] = fmaf(xv, hi16(p1.y), acc[11]);
    acc[12] = fmaf(xv, lo16(p1.z), acc[12]); acc[13] = fmaf(xv, hi16(p1.z), acc[13]);
    acc[14] = fmaf(xv, lo16(p1.w), acc[14]); acc[15] = fmaf(xv, hi16(p1.w), acc[15]);
  }
  int row = row0 + r;
  if (row < N_NODES) {
    if (blockIdx.y == 0) {
      unsigned int* op = xlp + (size_t)row * 64;
      uint4 o;
      unsigned int* ou = (unsigned int*)&o;
#pragma unroll
      for (int t = 0; t < 4; t++) {
        float f0 = fin(acc[2 * t]     + loadF(bb, fB, cg * 8 + 2 * t));
        float f1 = fin(acc[2 * t + 1] + loadF(bb, fB, cg * 8 + 2 * t + 1));
        ou[t] = (unsigned)f2bf(f0) | ((unsigned)f2bf(f1) << 16);
      }
      *(uint4*)(op + cg * 4) = o;
#pragma unroll
      for (int t = 0; t < 4; t++) {
        float f0 = fin(acc[8 + 2 * t]     + loadF(bb, fB, 64 + cg * 8 + 2 * t));
        float f1 = fin(acc[8 + 2 * t + 1] + loadF(bb, fB, 64 + cg * 8 + 2 * t + 1));
        ou[t] = (unsigned)f2bf(f0) | ((unsigned)f2bf(f1) << 16);
      }
      *(uint4*)(op + 32 + cg * 4) = o;
    } else {
      float* op = xr + (size_t)row * 128;
#pragma unroll
      for (int j = 0; j < 8; j++) op[cg * 8 + j]      = fin(acc[j]     + loadF(bb, fB, cg * 8 + j));
#pragma unroll
      for (int j = 0; j < 8; j++) op[64 + cg * 8 + j] = fin(acc[8 + j] + loadF(bb, fB, 64 + cg * 8 + j));
    }
  }
}

// ---------- layer-2 GEMM: xl2(packed bf16) / xr2(f32) = h@W + b ----------
__global__ __launch_bounds__(256) void k_gemm2(
    const float* __restrict__ h,
    const void* __restrict__ Wl, const void* __restrict__ bl,
    const void* __restrict__ Wr, const void* __restrict__ br,
    const int* __restrict__ flags,
    unsigned int* __restrict__ xlp, float* __restrict__ xr)
{
  __shared__ float hs[32 * 132];
  __shared__ unsigned short ws[128 * 64];
  const void* W  = blockIdx.y ? Wr : Wl;
  const void* bb = blockIdx.y ? br : bl;
  int fW = blockIdx.y ? flags[11] : flags[9];
  int fB = blockIdx.y ? flags[12] : flags[10];
  int tid = threadIdx.x;
  int row0 = blockIdx.x * 32;
  stageW(ws, W, 128 * 64, fW, tid);
  for (int i = tid * 4; i < 32 * 128; i += 1024) {
    int r = i >> 7, k = i & 127;
    int row = row0 + r;
    float4 v = make_float4(0.f, 0.f, 0.f, 0.f);
    if (row < N_NODES) v = *(const float4*)(h + (size_t)row * 128 + k);
    *(float4*)(hs + r * 132 + k) = v;
  }
  __syncthreads();
  int r = tid >> 3, cg = tid & 7;
  float acc[8];
#pragma unroll
  for (int j = 0; j < 8; j++) acc[j] = 0.f;
#pragma unroll 4
  for (int k = 0; k < 128; k++) {
    float hv = hs[r * 132 + k];
    uint4 p = *(const uint4*)(ws + k * 64 + cg * 8);
    acc[0] = fmaf(hv, lo16(p.x), acc[0]); acc[1] = fmaf(hv, hi16(p.x), acc[1]);
    acc[2] = fmaf(hv, lo16(p.y), acc[2]); acc[3] = fmaf(hv, hi16(p.y), acc[3]);
    acc[4] = fmaf(hv, lo16(p.z), acc[4]); acc[5] = fmaf(hv, hi16(p.z), acc[5]);
    acc[6] = fmaf(hv, lo16(p.w), acc[6]); acc[7] = fmaf(hv, hi16(p.w), acc[7]);
  }
  int row = row0 + r;
  if (row < N_NODES) {
    if (blockIdx.y == 0) {
      uint4 o;
      unsigned int* ou = (unsigned int*)&o;
#pragma unroll
      for (int t = 0; t < 4; t++) {
        float f0 = fin(acc[2 * t]     + loadF(bb, fB, cg * 8 + 2 * t));
        float f1 = fin(acc[2 * t + 1] + loadF(bb, fB, cg * 8 + 2 * t + 1));
        ou[t] = (unsigned)f2bf(f0) | ((unsigned)f2bf(f1) << 16);
      }
      *(uint4*)(xlp + (size_t)row * 32 + cg * 4) = o;
    } else {
      float* op = xr + (size_t)row * 64;
#pragma unroll
      for (int j = 0; j < 8; j++) op[cg * 8 + j] = fin(acc[j] + loadF(bb, fB, cg * 8 + j));
    }
  }
}

// ---------- CSR build ----------
__global__ __launch_bounds__(256) void k_hist(const int* __restrict__ ei, int* __restrict__ counts)
{
  int e = blockIdx.x * 256 + threadIdx.x;
  if (e < N_EDGES) {
    int d = ei[N_EDGES + e]; if ((unsigned)d >= N_NODES) d = 0;
    atomicAdd(&counts[d], 1);
  }
}

__global__ __launch_bounds__(256) void k_scan1(const int* __restrict__ counts,
                                               int* __restrict__ row_ptr, int* __restrict__ bsum)
{
  __shared__ int lds[256];
  int t = threadIdx.x;
  int base = blockIdx.x * 1024 + t * 4;
  int c0 = (base + 0) < N_NODES ? counts[base + 0] : 0;
  int c1 = (base + 1) < N_NODES ? counts[base + 1] : 0;
  int c2 = (base + 2) < N_NODES ? counts[base + 2] : 0;
  int c3 = (base + 3) < N_NODES ? counts[base + 3] : 0;
  int s = c0 + c1 + c2 + c3;
  lds[t] = s; __syncthreads();
  for (int off = 1; off < 256; off <<= 1) {
    int v = (t >= off) ? lds[t - off] : 0;
    __syncthreads();
    lds[t] += v;
    __syncthreads();
  }
  int incl = lds[t];
  int excl = incl - s;
  if (base + 0 < N_NODES) row_ptr[base + 0] = excl;
  if (base + 1 < N_NODES) row_ptr[base + 1] = excl + c0;
  if (base + 2 < N_NODES) row_ptr[base + 2] = excl + c0 + c1;
  if (base + 3 < N_NODES) row_ptr[base + 3] = excl + c0 + c1 + c2;
  if (t == 255) bsum[blockIdx.x] = incl;
}

__global__ __launch_bounds__(64) void k_scan2(int* __restrict__ bsum, int nb)
{
  __shared__ int l[64];
  int t = threadIdx.x;
  if (t < nb) l[t] = bsum[t];
  __syncthreads();
  if (t == 0) { int run = 0; for (int i = 0; i < nb; i++) { int v = l[i]; l[i] = run; run += v; } }
  __syncthreads();
  if (t < nb) bsum[t] = l[t];
}

__global__ __launch_bounds__(256) void k_scan3(int* __restrict__ row_ptr, int* __restrict__ cursor,
                                               const int* __restrict__ bsum)
{
  int t = threadIdx.x;
  int base = blockIdx.x * 1024 + t * 4;
  int add = bsum[blockIdx.x];
#pragma unroll
  for (int j = 0; j < 4; j++) {
    int i = base + j;
    if (i < N_NODES) { int v = row_ptr[i] + add; row_ptr[i] = v; cursor[i] = v; }
  }
  if (blockIdx.x == 0 && t == 0) row_ptr[N_NODES] = N_EDGES;
}

// writes col (edge id per CSR slot), pos (CSR slot per edge), srcs (src node per CSR slot)
__global__ __launch_bounds__(256) void k_scatter(const int* __restrict__ ei,
                                                 int* __restrict__ cursor, int* __restrict__ col,
                                                 int* __restrict__ pos, int* __restrict__ srcs)
{
  int e = blockIdx.x * 256 + threadIdx.x;
  if (e < N_EDGES) {
    int d = ei[N_EDGES + e]; if ((unsigned)d >= N_NODES) d = 0;
    int s = ei[e];           if ((unsigned)s >= N_NODES) s = 0;
    int p = atomicAdd(&cursor[d], 1);
    if ((unsigned)p < N_EDGES) { col[p] = e; pos[e] = p; srcs[p] = s; }
  }
}

// ---------- fused layer-1: scores + softmax + aggregate + ELU ----------
// wave per node; ee1u is CSR-ordered: row j <-> CSR slot j (sequential stream)
__global__ __launch_bounds__(256) void k_fused1(
    const int* __restrict__ srcs, const int* __restrict__ row_ptr, const int* __restrict__ col,
    const unsigned int* __restrict__ xlp, const float* __restrict__ xr,
    const unsigned int* __restrict__ ee1u,
    const void* __restrict__ ea, const void* __restrict__ We,
    const void* __restrict__ att, const void* __restrict__ bias,
    const int* __restrict__ flags, int use_ee,
    float* __restrict__ hout)
{
  __shared__ unsigned short wes[32 * 128];   // fallback only
  __shared__ float at[128];
  int tid = threadIdx.x;
  if (!use_ee) stageW(wes, We, 4096, flags[6], tid);
  if (tid < 128) at[tid] = loadF(att, flags[7], tid);
  __syncthreads();
  int i = blockIdx.x * 4 + (tid >> 6);
  int lane = tid & 63;
  float at0 = at[2 * lane], at1 = at[2 * lane + 1];
  float2 xrv = *(const float2*)(xr + (size_t)i * 128 + 2 * lane);
  int p0 = row_ptr[i], p1 = row_ptr[i + 1];
  float acc0 = 0.f, acc1 = 0.f, den = 0.f;
  int fEA = flags[1];
  const unsigned int* wep = (const unsigned int*)wes;
  if (use_ee) {
    int j = p0;
    for (; j + 4 <= p1; j += 4) {
      int s0 = srcs[j], s1 = srcs[j + 1], s2 = srcs[j + 2], s3 = srcs[j + 3];
      unsigned int ue0 = ee1u[(size_t)(j + 0) * 64 + lane];
      unsigned int ue1 = ee1u[(size_t)(j + 1) * 64 + lane];
      unsigned int ue2 = ee1u[(size_t)(j + 2) * 64 + lane];
      unsigned int ue3 = ee1u[(size_t)(j + 3) * 64 + lane];
      unsigned int ux0 = xlp[(size_t)s0 * 64 + lane];
      unsigned int ux1 = xlp[(size_t)s1 * 64 + lane];
      unsigned int ux2 = xlp[(size_t)s2 * 64 + lane];
      unsigned int ux3 = xlp[(size_t)s3 * 64 + lane];
#pragma unroll
      for (int q = 0; q < 4; q++) {
        unsigned int ux = q == 0 ? ux0 : q == 1 ? ux1 : q == 2 ? ux2 : ux3;
        unsigned int ue = q == 0 ? ue0 : q == 1 ? ue1 : q == 2 ? ue2 : ue3;
        float x0 = lo16(ux), x1 = hi16(ux);
        float m0 = x0 + xrv.x + lo16(ue);
        float m1 = x1 + xrv.y + hi16(ue);
        m0 = m0 > 0.f ? m0 : 0.2f * m0;
        m1 = m1 > 0.f ? m1 : 0.2f * m1;
        float pl = fmaf(at0, m0, at1 * m1);
        pl += __shfl_xor(pl, 1, 64);
        pl += __shfl_xor(pl, 2, 64);
        pl += __shfl_xor(pl, 4, 64);
        pl += __shfl_xor(pl, 8, 64);
        float w = __expf(fminf(pl, 25.f));
        acc0 = fmaf(w, x0, acc0); acc1 = fmaf(w, x1, acc1); den += w;
      }
    }
    for (; j < p1; j++) {
      int s = srcs[j];
      unsigned int ue = ee1u[(size_t)j * 64 + lane];
      unsigned int ux = xlp[(size_t)s * 64 + lane];
      float x0 = lo16(ux), x1 = hi16(ux);
      float m0 = x0 + xrv.x + lo16(ue);
      float m1 = x1 + xrv.y + hi16(ue);
      m0 = m0 > 0.f ? m0 : 0.2f * m0;
      m1 = m1 > 0.f ? m1 : 0.2f * m1;
      float pl = fmaf(at0, m0, at1 * m1);
      pl += __shfl_xor(pl, 1, 64);
      pl += __shfl_xor(pl, 2, 64);
      pl += __shfl_xor(pl, 4, 64);
      pl += __shfl_xor(pl, 8, 64);
      float w = __expf(fminf(pl, 25.f));
      acc0 = fmaf(w, x0, acc0); acc1 = fmaf(w, x1, acc1); den += w;
    }
  } else {
    for (int j = p0; j < p1; j++) {
      int e = col[j];
      int s = srcs[j];
      unsigned int ux = xlp[(size_t)s * 64 + lane];
      float x0 = lo16(ux), x1 = hi16(ux);
      float eav = (lane < 32) ? loadF(ea, fEA, (size_t)e * 32 + lane) : 0.f;
      float e0 = 0.f, e1 = 0.f;
#pragma unroll
      for (int k = 0; k < 32; k++) {
        float av = __shfl(eav, k, 64);
        unsigned int p = wep[k * 64 + lane];
        e0 = fmaf(av, lo16(p), e0);
        e1 = fmaf(av, hi16(p), e1);
      }
      float m0 = x0 + xrv.x + e0;
      float m1 = x1 + xrv.y + e1;
      m0 = m0 > 0.f ? m0 : 0.2f * m0;
      m1 = m1 > 0.f ? m1 : 0.2f * m1;
      float pl = fmaf(at0, m0, at1 * m1);
      pl += __shfl_xor(pl, 1, 64);
      pl += __shfl_xor(pl, 2, 64);
      pl += __shfl_xor(pl, 4, 64);
      pl += __shfl_xor(pl, 8, 64);
      float w = __expf(fminf(pl, 25.f));
      acc0 = fmaf(w, x0, acc0); acc1 = fmaf(w, x1, acc1); den += w;
    }
  }
  float inv = 1.f / (den + 1e-16f);
  float o0 = fin(fmaf(acc0, inv, loadF(bias, flags[8], 2 * lane)));
  float o1 = fin(fmaf(acc1, inv, loadF(bias, flags[8], 2 * lane + 1)));
  o0 = o0 > 0.f ? o0 : __expf(o0) - 1.f;
  o1 = o1 > 0.f ? o1 : __expf(o1) - 1.f;
  *(float2*)(hout + (size_t)i * 128 + 2 * lane) = make_float2(o0, o1);
}

// ---------- fused layer-2: H=1, C=64; write final out ----------
__global__ __launch_bounds__(256) void k_fused2(
    const int* __restrict__ srcs, const int* __restrict__ row_ptr, const int* __restrict__ col,
    const unsigned int* __restrict__ xlp, const float* __restrict__ xr,
    const unsigned int* __restrict__ ee2u,
    const void* __restrict__ ea, const void* __restrict__ We,
    const void* __restrict__ att, const void* __restrict__ bias,
    const int* __restrict__ flags, int use_ee,
    void* __restrict__ out)
{
  __shared__ unsigned short wes[32 * 64];
  __shared__ float at[64];
  int tid = threadIdx.x;
  if (!use_ee) stageW(wes, We, 2048, flags[13], tid);
  if (tid < 64) at[tid] = loadF(att, flags[14], tid);
  __syncthreads();
  int i = blockIdx.x * 4 + (tid >> 6);
  int lane = tid & 63;
  float atv = at[lane];
  float xrv = xr[(size_t)i * 64 + lane];
  int p0 = row_ptr[i], p1 = row_ptr[i + 1];
  float acc = 0.f, den = 0.f;
  int fEA = flags[1];
  const unsigned short* xlb = (const unsigned short*)xlp;
  const unsigned short* ee2s = (const unsigned short*)ee2u;
  if (use_ee) {
    int j = p0;
    for (; j + 4 <= p1; j += 4) {
      int s0 = srcs[j], s1 = srcs[j + 1], s2 = srcs[j + 2], s3 = srcs[j + 3];
      unsigned short e0s = ee2s[(size_t)(j + 0) * 64 + lane];
      unsigned short e1s = ee2s[(size_t)(j + 1) * 64 + lane];
      unsigned short e2s = ee2s[(size_t)(j + 2) * 64 + lane];
      unsigned short e3s = ee2s[(size_t)(j + 3) * 64 + lane];
      unsigned short x0s = xlb[(size_t)s0 * 64 + lane];
      unsigned short x1s = xlb[(size_t)s1 * 64 + lane];
      unsigned short x2s = xlb[(size_t)s2 * 64 + lane];
      unsigned short x3s = xlb[(size_t)s3 * 64 + lane];
#pragma unroll
      for (int q = 0; q < 4; q++) {
        float xv = bf2f(q == 0 ? x0s : q == 1 ? x1s : q == 2 ? x2s : x3s);
        float ee = bf2f(q == 0 ? e0s : q == 1 ? e1s : q == 2 ? e2s : e3s);
        float m = xv + xrv + ee;
        m = m > 0.f ? m : 0.2f * m;
        float pl = atv * m;
        pl += __shfl_xor(pl, 1, 64);
        pl += __shfl_xor(pl, 2, 64);
        pl += __shfl_xor(pl, 4, 64);
        pl += __shfl_xor(pl, 8, 64);
        pl += __shfl_xor(pl, 16, 64);
        pl += __shfl_xor(pl, 32, 64);
        float w = __expf(fminf(pl, 25.f));
        acc = fmaf(w, xv, acc); den += w;
      }
    }
    for (; j < p1; j++) {
      int s = srcs[j];
      float xv = bf2f(xlb[(size_t)s * 64 + lane]);
      float ee = bf2f(ee2s[(size_t)j * 64 + lane]);
      float m = xv + xrv + ee;
      m = m > 0.f ? m : 0.2f * m;
      float pl = atv * m;
      pl += __shfl_xor(pl, 1, 64);
      pl += __shfl_xor(pl, 2, 64);
      pl += __shfl_xor(pl, 4, 64);
      pl += __shfl_xor(pl, 8, 64);
      pl += __shfl_xor(pl, 16, 64);
      pl += __shfl_xor(pl, 32, 64);
      float w = __expf(fminf(pl, 25.f));
      acc = fmaf(w, xv, acc); den += w;
    }
  } else {
    for (int j = p0; j < p1; j++) {
      int e = col[j];
      int s = srcs[j];
      float xv = bf2f(xlb[(size_t)s * 64 + lane]);
      float eav = (lane < 32) ? loadF(ea, fEA, (size_t)e * 32 + lane) : 0.f;
      float ee = 0.f;
#pragma unroll
      for (int k = 0; k < 32; k++) {
        float av = __shfl(eav, k, 64);
        ee = fmaf(av, bf2f(wes[k * 64 + lane]), ee);
      }
      float m = xv + xrv + ee;
      m = m > 0.f ? m : 0.2f * m;
      float pl = atv * m;
      pl += __shfl_xor(pl, 1, 64);
      pl += __shfl_xor(pl, 2, 64);
      pl += __shfl_xor(pl, 4, 64);
      pl += __shfl_xor(pl, 8, 64);
      pl += __shfl_xor(pl, 16, 64);
      pl += __shfl_xor(pl, 32, 64);
      float w = __expf(fminf(pl, 25.f));
      acc = fmaf(w, xv, acc); den += w;
    }
  }
  float inv = 1.f / (den + 1e-16f);
  float o = fin(fmaf(acc, inv, loadF(bias, flags[15], lane)));
  if (flags[0]) ((float*)out)[(size_t)i * 64 + lane] = o;
  else ((unsigned short*)out)[(size_t)i * 64 + lane] = f2bf(o);
}

extern "C" void kernel_launch(void* const* d_in, const int* in_sizes, int n_in,
                              void* d_out, int out_size, void* d_ws, size_t ws_size,
                              hipStream_t stream)
{
  (void)n_in; (void)out_size;
  const void* x    = d_in[0];
  const int*  ei   = (const int*)d_in[1];
  const void* ea   = d_in[2];
  const void* Wl1  = d_in[3];
  const void* bl1  = d_in[4];
  const void* Wr1  = d_in[5];
  const void* br1  = d_in[6];
  const void* We1  = d_in[7];
  const void* att1 = d_in[8];
  const void* bias1= d_in[9];
  const void* Wl2  = d_in[10];
  const void* bl2  = d_in[11];
  const void* Wr2  = d_in[12];
  const void* br2  = d_in[13];
  const void* We2  = d_in[14];
  const void* att2 = d_in[15];
  const void* bias2= d_in[16];

  char* ws = (char*)d_ws;
  size_t off = 0;
  auto take = [&](size_t bytes) -> char* {
    char* p = ws + off;
    off += (bytes + 255) & ~(size_t)255;
    return p;
  };
  unsigned int* xl1p = (unsigned int*)take((size_t)N_NODES * 64 * 4);   // 12.8 MB
  float* xr1    = (float*)take((size_t)N_NODES * 128 * 4);              // 25.6 MB
  float* hbuf   = (float*)take((size_t)N_NODES * 128 * 4);              // 25.6 MB
  int*   counts = (int*)  take((size_t)N_NODES * 4);
  int*   row_ptr= (int*)  take((size_t)(N_NODES + 1) * 4);
  int*   cursor = (int*)  take((size_t)N_NODES * 4);
  int*   col    = (int*)  take((size_t)N_EDGES * 4);
  int*   pos    = (int*)  take((size_t)N_EDGES * 4);
  int*   srcs   = (int*)  take((size_t)N_EDGES * 4);
  int*   bsum   = (int*)  take(64 * 4);
  int*   flags  = (int*)  take(64 * 4);
  size_t base_end = off;
  unsigned int* ee1u = (unsigned int*)take((size_t)N_EDGES * 64 * 4);  // 204.8 MB
  unsigned int* ee2u = (unsigned int*)take((size_t)N_EDGES * 32 * 4);  // 102.4 MB
  int use_ee = (off <= ws_size) ? 1 : 0;
  if (!use_ee) { ee1u = (unsigned int*)(ws + base_end); ee2u = ee1u; }
  unsigned int* xl2p = xl1p;
  float* xr2 = xr1;

  Ptrs tl;
  const int map[16] = {0, 2, 3, 4, 5, 6, 7, 8, 9, 10, 11, 12, 13, 14, 15, 16};
  for (int j = 0; j < 16; j++) { tl.p[j] = d_in[map[j]]; tl.n[j] = in_sizes[map[j]]; }

  int nb = (N_NODES + 1023) / 1024;
  k_detect<<<16, 256, 0, stream>>>(tl, flags);
  k_zero<<<(N_NODES + 255) / 256, 256, 0, stream>>>(counts, N_NODES);
  k_gemm1<<<dim3((N_NODES + 31) / 32, 2), 256, 0, stream>>>(x, Wl1, bl1, Wr1, br1, flags, xl1p, xr1);
  k_hist<<<(N_EDGES + 255) / 256, 256, 0, stream>>>(ei, counts);
  k_scan1<<<nb, 256, 0, stream>>>(counts, row_ptr, bsum);
  k_scan2<<<1, 64, 0, stream>>>(bsum, nb);
  k_scan3<<<nb, 256, 0, stream>>>(row_ptr, cursor, bsum);
  k_scatter<<<(N_EDGES + 255) / 256, 256, 0, stream>>>(ei, cursor, col, pos, srcs);
  if (use_ee)
    k_ee_mfma<<<N_EDGES / 128, 256, 0, stream>>>(ea, We1, We2, pos, flags, ee1u, ee2u);
  k_fused1<<<N_NODES / 4, 256, 0, stream>>>(srcs, row_ptr, col, xl1p, xr1, ee1u,
                                            ea, We1, att1, bias1, flags, use_ee, hbuf);
  k_gemm2<<<dim3((N_NODES + 31) / 32, 2), 256, 0, stream>>>(hbuf, Wl2, bl2, Wr2, br2, flags, xl2p, xr2);
  k_fused2<<<N_NODES / 4, 256, 0, stream>>>(srcs, row_ptr, col, xl2p, xr2, ee2u,
                                            ea, We2, att2, bias2, flags, use_ee, d_out);
}

// Round 7
// 741.958 us; speedup vs baseline: 2.0542x; 1.1524x over previous
//
#include <hip/hip_runtime.h>
#include <stdint.h>

#define N_NODES 50000
#define N_EDGES 800000

// flag indices: 0:x 1:ea 2:Wl1 3:bl1 4:Wr1 5:br1 6:We1 7:att1 8:bias1
//               9:Wl2 10:bl2 11:Wr2 12:br2 13:We2 14:att2 15:bias2
struct Ptrs { const void* p[16]; int n[16]; };

typedef __attribute__((ext_vector_type(8))) short bf16x8;
typedef __attribute__((ext_vector_type(4))) float f32x4;

__device__ __forceinline__ float bf2f(unsigned short u){
  union { unsigned int i; float f; } v; v.i = ((unsigned int)u) << 16; return v.f;
}
__device__ __forceinline__ float lo16(unsigned int u){ union { unsigned int i; float f; } v; v.i = u << 16; return v.f; }
__device__ __forceinline__ float hi16(unsigned int u){ union { unsigned int i; float f; } v; v.i = u & 0xffff0000u; return v.f; }
__device__ __forceinline__ unsigned short f2bf(float f){
  if (!(f == f)) return 0;
  unsigned int x = __float_as_uint(f);
  unsigned int r = (x + 0x7fffu + ((x >> 16) & 1u)) >> 16;
  return (unsigned short)r;
}
__device__ __forceinline__ float fin(float v){
  if (!(v == v)) return 0.f;
  return fminf(fmaxf(v, -1e30f), 1e30f);
}
__device__ __forceinline__ float loadF(const void* p, int f32, size_t idx){
  return f32 ? ((const float*)p)[idx] : bf2f(((const unsigned short*)p)[idx]);
}

// stage n bf16 elems of W (bf16 or f32 source) into LDS; n multiple of 2048
__device__ __forceinline__ void stageW(unsigned short* dst, const void* src, int n, int f32, int tid){
  if (f32) {
    for (int i = tid * 8; i < n; i += 2048) {
      float4 a = *(const float4*)((const float*)src + i);
      float4 b = *(const float4*)((const float*)src + i + 4);
      uint4 u;
      u.x = (unsigned)f2bf(a.x) | ((unsigned)f2bf(a.y) << 16);
      u.y = (unsigned)f2bf(a.z) | ((unsigned)f2bf(a.w) << 16);
      u.z = (unsigned)f2bf(b.x) | ((unsigned)f2bf(b.y) << 16);
      u.w = (unsigned)f2bf(b.z) | ((unsigned)f2bf(b.w) << 16);
      *(uint4*)(dst + i) = u;
    }
  } else {
    for (int i = tid * 8; i < n; i += 2048)
      *(uint4*)(dst + i) = *(const uint4*)((const unsigned short*)src + i);
  }
}

// ---------- dtype detect ----------
__global__ __launch_bounds__(256) void k_detect(Ptrs tl, int* __restrict__ flags)
{
  __shared__ int red[256];
  int b = blockIdx.x, t = threadIdx.x;
  const unsigned short* p = (const unsigned short*)tl.p[b];
  int n = tl.n[b]; if (n > 16384) n = 16384;
  int crazy = 0;
  for (int i = t; i < n; i += 256) {
    unsigned short u = p[i];
    if (u) {
      int ex = (u >> 7) & 0xFF;
      if (ex == 0xFF || ex < 0x60) crazy++;
    }
  }
  red[t] = crazy; __syncthreads();
  for (int off = 128; off; off >>= 1) { if (t < off) red[t] += red[t + off]; __syncthreads(); }
  if (t == 0) flags[b] = (red[0] * 10 > n) ? 1 : 0;
}

__global__ __launch_bounds__(256) void k_zero(int* __restrict__ p, int n)
{
  int i = blockIdx.x * 256 + threadIdx.x;
  if (i < n) p[i] = 0;
}

// ---------- layer-1 GEMM: xl1p / xr1p (both packed bf16 [N,64] uints) ----------
__global__ __launch_bounds__(256) void k_gemm1(
    const void* __restrict__ x,
    const void* __restrict__ Wl, const void* __restrict__ bl,
    const void* __restrict__ Wr, const void* __restrict__ br,
    const int* __restrict__ flags,
    unsigned int* __restrict__ xlp, unsigned int* __restrict__ xrp)
{
  __shared__ float xs[32 * 132];
  __shared__ unsigned short ws[128 * 128];
  const void* W  = blockIdx.y ? Wr : Wl;
  const void* bb = blockIdx.y ? br : bl;
  int fW = blockIdx.y ? flags[4] : flags[2];
  int fB = blockIdx.y ? flags[5] : flags[3];
  int fX = flags[0];
  unsigned int* outp = blockIdx.y ? xrp : xlp;
  int tid = threadIdx.x;
  int row0 = blockIdx.x * 32;
  stageW(ws, W, 128 * 128, fW, tid);
  for (int i = tid * 4; i < 32 * 128; i += 1024) {
    int r = i >> 7, k = i & 127;
    int row = row0 + r;
    float4 v = make_float4(0.f, 0.f, 0.f, 0.f);
    if (row < N_NODES) {
      if (fX) v = *(const float4*)((const float*)x + (size_t)row * 128 + k);
      else {
        uint2 u = *(const uint2*)((const unsigned short*)x + (size_t)row * 128 + k);
        v.x = lo16(u.x); v.y = hi16(u.x); v.z = lo16(u.y); v.w = hi16(u.y);
      }
    }
    *(float4*)(xs + r * 132 + k) = v;
  }
  __syncthreads();
  int r = tid >> 3, cg = tid & 7;
  float acc[16];
#pragma unroll
  for (int j = 0; j < 16; j++) acc[j] = 0.f;
#pragma unroll 4
  for (int k = 0; k < 128; k++) {
    float xv = xs[r * 132 + k];
    uint4 p0 = *(const uint4*)(ws + k * 128 + cg * 8);
    uint4 p1 = *(const uint4*)(ws + k * 128 + 64 + cg * 8);
    acc[0]  = fmaf(xv, lo16(p0.x), acc[0]);  acc[1]  = fmaf(xv, hi16(p0.x), acc[1]);
    acc[2]  = fmaf(xv, lo16(p0.y), acc[2]);  acc[3]  = fmaf(xv, hi16(p0.y), acc[3]);
    acc[4]  = fmaf(xv, lo16(p0.z), acc[4]);  acc[5]  = fmaf(xv, hi16(p0.z), acc[5]);
    acc[6]  = fmaf(xv, lo16(p0.w), acc[6]);  acc[7]  = fmaf(xv, hi16(p0.w), acc[7]);
    acc[8]  = fmaf(xv, lo16(p1.x), acc[8]);  acc[9]  = fmaf(xv, hi16(p1.x), acc[9]);
    acc[10] = fmaf(xv, lo16(p1.y), acc[10]); acc[11] = fmaf(xv, hi16(p1.y), acc[11]);
    acc[12] = fmaf(xv, lo16(p1.z), acc[12]); acc[13] = fmaf(xv, hi16(p1.z), acc[13]);
    acc[14] = fmaf(xv, lo16(p1.w), acc[14]); acc[15] = fmaf(xv, hi16(p1.w), acc[15]);
  }
  int row = row0 + r;
  if (row < N_NODES) {
    unsigned int* op = outp + (size_t)row * 64;
    uint4 o;
    unsigned int* ou = (unsigned int*)&o;
#pragma unroll
    for (int t = 0; t < 4; t++) {
      float f0 = fin(acc[2 * t]     + loadF(bb, fB, cg * 8 + 2 * t));
      float f1 = fin(acc[2 * t + 1] + loadF(bb, fB, cg * 8 + 2 * t + 1));
      ou[t] = (unsigned)f2bf(f0) | ((unsigned)f2bf(f1) << 16);
    }
    *(uint4*)(op + cg * 4) = o;
#pragma unroll
    for (int t = 0; t < 4; t++) {
      float f0 = fin(acc[8 + 2 * t]     + loadF(bb, fB, 64 + cg * 8 + 2 * t));
      float f1 = fin(acc[8 + 2 * t + 1] + loadF(bb, fB, 64 + cg * 8 + 2 * t + 1));
      ou[t] = (unsigned)f2bf(f0) | ((unsigned)f2bf(f1) << 16);
    }
    *(uint4*)(op + 32 + cg * 4) = o;
  }
}

// ---------- layer-2 GEMM: xl2p / xr2p (packed bf16 [N,32] uints) ----------
__global__ __launch_bounds__(256) void k_gemm2(
    const float* __restrict__ h,
    const void* __restrict__ Wl, const void* __restrict__ bl,
    const void* __restrict__ Wr, const void* __restrict__ br,
    const int* __restrict__ flags,
    unsigned int* __restrict__ xlp, unsigned int* __restrict__ xrp)
{
  __shared__ float hs[32 * 132];
  __shared__ unsigned short ws[128 * 64];
  const void* W  = blockIdx.y ? Wr : Wl;
  const void* bb = blockIdx.y ? br : bl;
  int fW = blockIdx.y ? flags[11] : flags[9];
  int fB = blockIdx.y ? flags[12] : flags[10];
  unsigned int* outp = blockIdx.y ? xrp : xlp;
  int tid = threadIdx.x;
  int row0 = blockIdx.x * 32;
  stageW(ws, W, 128 * 64, fW, tid);
  for (int i = tid * 4; i < 32 * 128; i += 1024) {
    int r = i >> 7, k = i & 127;
    int row = row0 + r;
    float4 v = make_float4(0.f, 0.f, 0.f, 0.f);
    if (row < N_NODES) v = *(const float4*)(h + (size_t)row * 128 + k);
    *(float4*)(hs + r * 132 + k) = v;
  }
  __syncthreads();
  int r = tid >> 3, cg = tid & 7;
  float acc[8];
#pragma unroll
  for (int j = 0; j < 8; j++) acc[j] = 0.f;
#pragma unroll 4
  for (int k = 0; k < 128; k++) {
    float hv = hs[r * 132 + k];
    uint4 p = *(const uint4*)(ws + k * 64 + cg * 8);
    acc[0] = fmaf(hv, lo16(p.x), acc[0]); acc[1] = fmaf(hv, hi16(p.x), acc[1]);
    acc[2] = fmaf(hv, lo16(p.y), acc[2]); acc[3] = fmaf(hv, hi16(p.y), acc[3]);
    acc[4] = fmaf(hv, lo16(p.z), acc[4]); acc[5] = fmaf(hv, hi16(p.z), acc[5]);
    acc[6] = fmaf(hv, lo16(p.w), acc[6]); acc[7] = fmaf(hv, hi16(p.w), acc[7]);
  }
  int row = row0 + r;
  if (row < N_NODES) {
    uint4 o;
    unsigned int* ou = (unsigned int*)&o;
#pragma unroll
    for (int t = 0; t < 4; t++) {
      float f0 = fin(acc[2 * t]     + loadF(bb, fB, cg * 8 + 2 * t));
      float f1 = fin(acc[2 * t + 1] + loadF(bb, fB, cg * 8 + 2 * t + 1));
      ou[t] = (unsigned)f2bf(f0) | ((unsigned)f2bf(f1) << 16);
    }
    *(uint4*)(outp + (size_t)row * 32 + cg * 4) = o;
  }
}

// ---------- CSR build ----------
__global__ __launch_bounds__(256) void k_hist(const int* __restrict__ ei, int* __restrict__ counts)
{
  int e = blockIdx.x * 256 + threadIdx.x;
  if (e < N_EDGES) {
    int d = ei[N_EDGES + e]; if ((unsigned)d >= N_NODES) d = 0;
    atomicAdd(&counts[d], 1);
  }
}

__global__ __launch_bounds__(256) void k_scan1(const int* __restrict__ counts,
                                               int* __restrict__ row_ptr, int* __restrict__ bsum)
{
  __shared__ int lds[256];
  int t = threadIdx.x;
  int base = blockIdx.x * 1024 + t * 4;
  int c0 = (base + 0) < N_NODES ? counts[base + 0] : 0;
  int c1 = (base + 1) < N_NODES ? counts[base + 1] : 0;
  int c2 = (base + 2) < N_NODES ? counts[base + 2] : 0;
  int c3 = (base + 3) < N_NODES ? counts[base + 3] : 0;
  int s = c0 + c1 + c2 + c3;
  lds[t] = s; __syncthreads();
  for (int off = 1; off < 256; off <<= 1) {
    int v = (t >= off) ? lds[t - off] : 0;
    __syncthreads();
    lds[t] += v;
    __syncthreads();
  }
  int incl = lds[t];
  int excl = incl - s;
  if (base + 0 < N_NODES) row_ptr[base + 0] = excl;
  if (base + 1 < N_NODES) row_ptr[base + 1] = excl + c0;
  if (base + 2 < N_NODES) row_ptr[base + 2] = excl + c0 + c1;
  if (base + 3 < N_NODES) row_ptr[base + 3] = excl + c0 + c1 + c2;
  if (t == 255) bsum[blockIdx.x] = incl;
}

__global__ __launch_bounds__(64) void k_scan2(int* __restrict__ bsum, int nb)
{
  __shared__ int l[64];
  int t = threadIdx.x;
  if (t < nb) l[t] = bsum[t];
  __syncthreads();
  if (t == 0) { int run = 0; for (int i = 0; i < nb; i++) { int v = l[i]; l[i] = run; run += v; } }
  __syncthreads();
  if (t < nb) bsum[t] = l[t];
}

__global__ __launch_bounds__(256) void k_scan3(int* __restrict__ row_ptr, int* __restrict__ cursor,
                                               const int* __restrict__ bsum)
{
  int t = threadIdx.x;
  int base = blockIdx.x * 1024 + t * 4;
  int add = bsum[blockIdx.x];
#pragma unroll
  for (int j = 0; j < 4; j++) {
    int i = base + j;
    if (i < N_NODES) { int v = row_ptr[i] + add; row_ptr[i] = v; cursor[i] = v; }
  }
  if (blockIdx.x == 0 && t == 0) row_ptr[N_NODES] = N_EDGES;
}

__global__ __launch_bounds__(256) void k_scatter(const int* __restrict__ ei,
                                                 int* __restrict__ cursor, int* __restrict__ col,
                                                 int* __restrict__ pos, int* __restrict__ srcs)
{
  int e = blockIdx.x * 256 + threadIdx.x;
  if (e < N_EDGES) {
    int d = ei[N_EDGES + e]; if ((unsigned)d >= N_NODES) d = 0;
    int s = ei[e];           if ((unsigned)s >= N_NODES) s = 0;
    int p = atomicAdd(&cursor[d], 1);
    if ((unsigned)p < N_EDGES) { col[p] = e; pos[e] = p; srcs[p] = s; }
  }
}

// ---------- layer-1 edge scores: MFMA ee (regs) + gather xl/xr + logit -> w1[pos,4] ----------
// block = 128 edges (4 waves x 2 tiles of 16). 8 MFMA tiles cover 128 channels.
__global__ __launch_bounds__(256) void k_score1(
    const void* __restrict__ ea, const int* __restrict__ ei, const int* __restrict__ pos,
    const unsigned int* __restrict__ xlp, const unsigned int* __restrict__ xrp,
    const void* __restrict__ We, const void* __restrict__ att,
    const int* __restrict__ flags, float* __restrict__ w1)
{
  __shared__ unsigned short wt[128 * 34];   // WeT[ch][k], stride 34 (odd dwords)
  __shared__ float at[128];
  int tid = threadIdx.x;
  {
    int f = flags[6];
    for (int i = tid; i < 4096; i += 256) {   // We[k][c] -> wt[c*34+k]
      int k = i >> 7, c = i & 127;
      wt[c * 34 + k] = f ? f2bf(((const float*)We)[i]) : ((const unsigned short*)We)[i];
    }
  }
  if (tid < 128) at[tid] = loadF(att, flags[7], tid);
  __syncthreads();
  int lane = tid & 63;
  int idx16 = lane & 15, quad = lane >> 4;
  bf16x8 af[8];
  float4 atv[8];
#pragma unroll
  for (int t = 0; t < 8; t++) {
    af[t]  = *(const bf16x8*)(wt + (t * 16 + idx16) * 34 + quad * 8);
    atv[t] = *(const float4*)(at + t * 16 + quad * 4);
  }
  int fEA = flags[1];
  size_t e0 = (size_t)blockIdx.x * 128 + (size_t)(tid >> 6) * 32;
#pragma unroll
  for (int tt = 0; tt < 2; tt++) {
    size_t e = e0 + tt * 16 + idx16;
    bf16x8 bfrag;
    if (fEA) {
      const float* p = (const float*)ea + e * 32 + quad * 8;
      float4 v0 = *(const float4*)p;
      float4 v1 = *(const float4*)(p + 4);
      unsigned short tmp[8] = { f2bf(v0.x), f2bf(v0.y), f2bf(v0.z), f2bf(v0.w),
                                f2bf(v1.x), f2bf(v1.y), f2bf(v1.z), f2bf(v1.w) };
      bfrag = *(const bf16x8*)tmp;
    } else {
      bfrag = *(const bf16x8*)((const unsigned short*)ea + e * 32 + quad * 8);
    }
    int s = ei[e];           if ((unsigned)s >= N_NODES) s = 0;
    int d = ei[N_EDGES + e]; if ((unsigned)d >= N_NODES) d = 0;
    size_t dp = (size_t)pos[e];
    float ph0 = 0.f, ph1 = 0.f, ph2 = 0.f, ph3 = 0.f;
#pragma unroll
    for (int t = 0; t < 8; t++) {
      f32x4 c = {0.f, 0.f, 0.f, 0.f};
      c = __builtin_amdgcn_mfma_f32_16x16x32_bf16(af[t], bfrag, c, 0, 0, 0);
      uint2 ux = *(const uint2*)(xlp + (size_t)s * 64 + t * 8 + quad * 2);
      uint2 ur = *(const uint2*)(xrp + (size_t)d * 64 + t * 8 + quad * 2);
      float z0 = c[0] + lo16(ux.x) + lo16(ur.x);
      float z1 = c[1] + hi16(ux.x) + hi16(ur.x);
      float z2 = c[2] + lo16(ux.y) + lo16(ur.y);
      float z3 = c[3] + hi16(ux.y) + hi16(ur.y);
      z0 = z0 > 0.f ? z0 : 0.2f * z0;
      z1 = z1 > 0.f ? z1 : 0.2f * z1;
      z2 = z2 > 0.f ? z2 : 0.2f * z2;
      z3 = z3 > 0.f ? z3 : 0.2f * z3;
      float pp = fmaf(atv[t].x, z0, fmaf(atv[t].y, z1, fmaf(atv[t].z, z2, atv[t].w * z3)));
      if (t < 2)      ph0 += pp;
      else if (t < 4) ph1 += pp;
      else if (t < 6) ph2 += pp;
      else            ph3 += pp;
    }
    ph0 += __shfl_xor(ph0, 16, 64); ph0 += __shfl_xor(ph0, 32, 64);
    ph1 += __shfl_xor(ph1, 16, 64); ph1 += __shfl_xor(ph1, 32, 64);
    ph2 += __shfl_xor(ph2, 16, 64); ph2 += __shfl_xor(ph2, 32, 64);
    ph3 += __shfl_xor(ph3, 16, 64); ph3 += __shfl_xor(ph3, 32, 64);
    float myp = quad == 0 ? ph0 : quad == 1 ? ph1 : quad == 2 ? ph2 : ph3;
    w1[dp * 4 + quad] = __expf(fminf(fin(myp), 25.f));
  }
}

// ---------- layer-2 edge scores: H=1, C=64 -> w2[pos] ----------
__global__ __launch_bounds__(256) void k_score2(
    const void* __restrict__ ea, const int* __restrict__ ei, const int* __restrict__ pos,
    const unsigned int* __restrict__ xlp, const unsigned int* __restrict__ xrp,
    const void* __restrict__ We, const void* __restrict__ att,
    const int* __restrict__ flags, float* __restrict__ w2)
{
  __shared__ unsigned short wt[64 * 34];
  __shared__ float at[64];
  int tid = threadIdx.x;
  {
    int f = flags[13];
    for (int i = tid; i < 2048; i += 256) {   // We[k][c] -> wt[c*34+k]
      int k = i >> 6, c = i & 63;
      wt[c * 34 + k] = f ? f2bf(((const float*)We)[i]) : ((const unsigned short*)We)[i];
    }
  }
  if (tid < 64) at[tid] = loadF(att, flags[14], tid);
  __syncthreads();
  int lane = tid & 63;
  int idx16 = lane & 15, quad = lane >> 4;
  bf16x8 af[4];
  float4 atv[4];
#pragma unroll
  for (int t = 0; t < 4; t++) {
    af[t]  = *(const bf16x8*)(wt + (t * 16 + idx16) * 34 + quad * 8);
    atv[t] = *(const float4*)(at + t * 16 + quad * 4);
  }
  int fEA = flags[1];
  size_t e0 = (size_t)blockIdx.x * 128 + (size_t)(tid >> 6) * 32;
#pragma unroll
  for (int tt = 0; tt < 2; tt++) {
    size_t e = e0 + tt * 16 + idx16;
    bf16x8 bfrag;
    if (fEA) {
      const float* p = (const float*)ea + e * 32 + quad * 8;
      float4 v0 = *(const float4*)p;
      float4 v1 = *(const float4*)(p + 4);
      unsigned short tmp[8] = { f2bf(v0.x), f2bf(v0.y), f2bf(v0.z), f2bf(v0.w),
                                f2bf(v1.x), f2bf(v1.y), f2bf(v1.z), f2bf(v1.w) };
      bfrag = *(const bf16x8*)tmp;
    } else {
      bfrag = *(const bf16x8*)((const unsigned short*)ea + e * 32 + quad * 8);
    }
    int s = ei[e];           if ((unsigned)s >= N_NODES) s = 0;
    int d = ei[N_EDGES + e]; if ((unsigned)d >= N_NODES) d = 0;
    size_t dp = (size_t)pos[e];
    float ph = 0.f;
#pragma unroll
    for (int t = 0; t < 4; t++) {
      f32x4 c = {0.f, 0.f, 0.f, 0.f};
      c = __builtin_amdgcn_mfma_f32_16x16x32_bf16(af[t], bfrag, c, 0, 0, 0);
      uint2 ux = *(const uint2*)(xlp + (size_t)s * 32 + t * 8 + quad * 2);
      uint2 ur = *(const uint2*)(xrp + (size_t)d * 32 + t * 8 + quad * 2);
      float z0 = c[0] + lo16(ux.x) + lo16(ur.x);
      float z1 = c[1] + hi16(ux.x) + hi16(ur.x);
      float z2 = c[2] + lo16(ux.y) + lo16(ur.y);
      float z3 = c[3] + hi16(ux.y) + hi16(ur.y);
      z0 = z0 > 0.f ? z0 : 0.2f * z0;
      z1 = z1 > 0.f ? z1 : 0.2f * z1;
      z2 = z2 > 0.f ? z2 : 0.2f * z2;
      z3 = z3 > 0.f ? z3 : 0.2f * z3;
      ph += fmaf(atv[t].x, z0, fmaf(atv[t].y, z1, fmaf(atv[t].z, z2, atv[t].w * z3)));
    }
    ph += __shfl_xor(ph, 16, 64);
    ph += __shfl_xor(ph, 32, 64);
    if (quad == 0) w2[dp] = __expf(fminf(fin(ph), 25.f));
  }
}

// ---------- layer-1 aggregate: w1 (CSR-seq) + xl gather -> ELU h[N,128] ----------
__global__ __launch_bounds__(256) void k_agg1(
    const int* __restrict__ srcs, const int* __restrict__ row_ptr,
    const unsigned int* __restrict__ xlp, const float* __restrict__ w1,
    const void* __restrict__ bias, const int* __restrict__ flags,
    float* __restrict__ hout)
{
  int tid = threadIdx.x;
  int i = blockIdx.x * 4 + (tid >> 6);
  int lane = tid & 63;
  int head = lane >> 4;
  int p0 = row_ptr[i], p1 = row_ptr[i + 1];
  float acc0 = 0.f, acc1 = 0.f, den = 0.f;
  int j = p0;
  for (; j + 4 <= p1; j += 4) {
    int s0 = srcs[j], s1 = srcs[j + 1], s2 = srcs[j + 2], s3 = srcs[j + 3];
    float wa = w1[(size_t)(j + 0) * 4 + head];
    float wb = w1[(size_t)(j + 1) * 4 + head];
    float wc = w1[(size_t)(j + 2) * 4 + head];
    float wd = w1[(size_t)(j + 3) * 4 + head];
    unsigned int ux0 = xlp[(size_t)s0 * 64 + lane];
    unsigned int ux1 = xlp[(size_t)s1 * 64 + lane];
    unsigned int ux2 = xlp[(size_t)s2 * 64 + lane];
    unsigned int ux3 = xlp[(size_t)s3 * 64 + lane];
    acc0 = fmaf(wa, lo16(ux0), acc0); acc1 = fmaf(wa, hi16(ux0), acc1);
    acc0 = fmaf(wb, lo16(ux1), acc0); acc1 = fmaf(wb, hi16(ux1), acc1);
    acc0 = fmaf(wc, lo16(ux2), acc0); acc1 = fmaf(wc, hi16(ux2), acc1);
    acc0 = fmaf(wd, lo16(ux3), acc0); acc1 = fmaf(wd, hi16(ux3), acc1);
    den += wa + wb + wc + wd;
  }
  for (; j < p1; j++) {
    int s = srcs[j];
    float w = w1[(size_t)j * 4 + head];
    unsigned int ux = xlp[(size_t)s * 64 + lane];
    acc0 = fmaf(w, lo16(ux), acc0);
    acc1 = fmaf(w, hi16(ux), acc1);
    den += w;
  }
  float inv = 1.f / (den + 1e-16f);
  float o0 = fin(fmaf(acc0, inv, loadF(bias, flags[8], 2 * lane)));
  float o1 = fin(fmaf(acc1, inv, loadF(bias, flags[8], 2 * lane + 1)));
  o0 = o0 > 0.f ? o0 : __expf(o0) - 1.f;
  o1 = o1 > 0.f ? o1 : __expf(o1) - 1.f;
  *(float2*)(hout + (size_t)i * 128 + 2 * lane) = make_float2(o0, o1);
}

// ---------- layer-2 aggregate: w2 (CSR-seq) + xl gather -> out [N,64] ----------
__global__ __launch_bounds__(256) void k_agg2(
    const int* __restrict__ srcs, const int* __restrict__ row_ptr,
    const unsigned int* __restrict__ xlp, const float* __restrict__ w2,
    const void* __restrict__ bias, const int* __restrict__ flags,
    void* __restrict__ out)
{
  int tid = threadIdx.x;
  int i = blockIdx.x * 4 + (tid >> 6);
  int lane = tid & 63;
  const unsigned short* xlb = (const unsigned short*)xlp;
  int p0 = row_ptr[i], p1 = row_ptr[i + 1];
  float acc = 0.f, den = 0.f;
  int j = p0;
  for (; j + 4 <= p1; j += 4) {
    int s0 = srcs[j], s1 = srcs[j + 1], s2 = srcs[j + 2], s3 = srcs[j + 3];
    float wa = w2[j], wb = w2[j + 1], wc = w2[j + 2], wd = w2[j + 3];
    unsigned short x0 = xlb[(size_t)s0 * 64 + lane];
    unsigned short x1 = xlb[(size_t)s1 * 64 + lane];
    unsigned short x2 = xlb[(size_t)s2 * 64 + lane];
    unsigned short x3 = xlb[(size_t)s3 * 64 + lane];
    acc = fmaf(wa, bf2f(x0), acc);
    acc = fmaf(wb, bf2f(x1), acc);
    acc = fmaf(wc, bf2f(x2), acc);
    acc = fmaf(wd, bf2f(x3), acc);
    den += wa + wb + wc + wd;
  }
  for (; j < p1; j++) {
    int s = srcs[j];
    float w = w2[j];
    acc = fmaf(w, bf2f(xlb[(size_t)s * 64 + lane]), acc);
    den += w;
  }
  float inv = 1.f / (den + 1e-16f);
  float o = fin(fmaf(acc, inv, loadF(bias, flags[15], lane)));
  if (flags[0]) ((float*)out)[(size_t)i * 64 + lane] = o;
  else ((unsigned short*)out)[(size_t)i * 64 + lane] = f2bf(o);
}

extern "C" void kernel_launch(void* const* d_in, const int* in_sizes, int n_in,
                              void* d_out, int out_size, void* d_ws, size_t ws_size,
                              hipStream_t stream)
{
  (void)n_in; (void)out_size; (void)ws_size;
  const void* x    = d_in[0];
  const int*  ei   = (const int*)d_in[1];
  const void* ea   = d_in[2];
  const void* Wl1  = d_in[3];
  const void* bl1  = d_in[4];
  const void* Wr1  = d_in[5];
  const void* br1  = d_in[6];
  const void* We1  = d_in[7];
  const void* att1 = d_in[8];
  const void* bias1= d_in[9];
  const void* Wl2  = d_in[10];
  const void* bl2  = d_in[11];
  const void* Wr2  = d_in[12];
  const void* br2  = d_in[13];
  const void* We2  = d_in[14];
  const void* att2 = d_in[15];
  const void* bias2= d_in[16];

  char* ws = (char*)d_ws;
  size_t off = 0;
  auto take = [&](size_t bytes) -> char* {
    char* p = ws + off;
    off += (bytes + 255) & ~(size_t)255;
    return p;
  };
  unsigned int* xl1p = (unsigned int*)take((size_t)N_NODES * 64 * 4);   // 12.8 MB
  unsigned int* xr1p = (unsigned int*)take((size_t)N_NODES * 64 * 4);   // 12.8 MB
  float* hbuf   = (float*)take((size_t)N_NODES * 128 * 4);              // 25.6 MB
  float* w1     = (float*)take((size_t)N_EDGES * 4 * 4);                // 12.8 MB
  int*   counts = (int*)  take((size_t)N_NODES * 4);
  int*   row_ptr= (int*)  take((size_t)(N_NODES + 1) * 4);
  int*   cursor = (int*)  take((size_t)N_NODES * 4);
  int*   col    = (int*)  take((size_t)N_EDGES * 4);
  int*   pos    = (int*)  take((size_t)N_EDGES * 4);
  int*   srcs   = (int*)  take((size_t)N_EDGES * 4);
  int*   bsum   = (int*)  take(64 * 4);
  int*   flags  = (int*)  take(64 * 4);
  unsigned int* xl2p = xl1p;      // layer-2 reuses ([N,32] <= [N,64])
  unsigned int* xr2p = xr1p;
  float* w2 = w1;                 // [E] <= [E,4]

  Ptrs tl;
  const int map[16] = {0, 2, 3, 4, 5, 6, 7, 8, 9, 10, 11, 12, 13, 14, 15, 16};
  for (int j = 0; j < 16; j++) { tl.p[j] = d_in[map[j]]; tl.n[j] = in_sizes[map[j]]; }

  int nb = (N_NODES + 1023) / 1024;
  k_detect<<<16, 256, 0, stream>>>(tl, flags);
  k_zero<<<(N_NODES + 255) / 256, 256, 0, stream>>>(counts, N_NODES);
  k_gemm1<<<dim3((N_NODES + 31) / 32, 2), 256, 0, stream>>>(x, Wl1, bl1, Wr1, br1, flags, xl1p, xr1p);
  k_hist<<<(N_EDGES + 255) / 256, 256, 0, stream>>>(ei, counts);
  k_scan1<<<nb, 256, 0, stream>>>(counts, row_ptr, bsum);
  k_scan2<<<1, 64, 0, stream>>>(bsum, nb);
  k_scan3<<<nb, 256, 0, stream>>>(row_ptr, cursor, bsum);
  k_scatter<<<(N_EDGES + 255) / 256, 256, 0, stream>>>(ei, cursor, col, pos, srcs);
  k_score1<<<N_EDGES / 128, 256, 0, stream>>>(ea, ei, pos, xl1p, xr1p, We1, att1, flags, w1);
  k_agg1<<<N_NODES / 4, 256, 0, stream>>>(srcs, row_ptr, xl1p, w1, bias1, flags, hbuf);
  k_gemm2<<<dim3((N_NODES + 31) / 32, 2), 256, 0, stream>>>(hbuf, Wl2, bl2, Wr2, br2, flags, xl2p, xr2p);
  k_score2<<<N_EDGES / 128, 256, 0, stream>>>(ea, ei, pos, xl2p, xr2p, We2, att2, flags, w2);
  k_agg2<<<N_NODES / 4, 256, 0, stream>>>(srcs, row_ptr, xl2p, w2, bias2, flags, d_out);
}